// Round 12
// baseline (1041.043 us; speedup 1.0000x reference)
//
#include <hip/hip_runtime.h>

// ObjectMsgEncoder on MI355X. f32 I/O, bf16 MFMA internally (f32 accumulate).
// R31 -> R32: extend the weight-residency lever. R31 proved the rec step time
// is EXACTLY proportional to per-step global weight traffic (~20 B/cy/CU:
// 128KB moved to LDS -> -25% launch time). Registers are the other on-chip
// store: block = 16 waves => VGPR cap 128; rec branch measured 64 => 64 free.
// Now: kt 0..1 of Whh in LDS (128KB, R31), kt 2..4 in REGISTERS (48 VGPR/thr,
// loaded once before the t-loop, never reloaded), only kt 5..7 (192KB/step)
// streams from L2. kt is compile-time under the unroll -> static selection,
// static register indexing. Weights bit-identical -> numerics unchanged.
// Everything else byte-identical to R31 (best: 1019.5us; k_mega 478).

typedef __attribute__((ext_vector_type(8))) short short8;
typedef __attribute__((ext_vector_type(4))) float f32x4;

__device__ __forceinline__ float b2f(unsigned short u){
  union { unsigned int i; float f; } v; v.i = ((unsigned int)u) << 16; return v.f;
}
__device__ __forceinline__ float u2f(unsigned int u){
  union { unsigned int i; float f; } v; v.i = u; return v.f;
}
__device__ __forceinline__ unsigned short f2b(float f){
  union { float f; unsigned int i; } v; v.f = f;
  return (unsigned short)((v.i + 0x8000u) >> 16);   // round-half-up
}
// pack two f32 -> bf16x2 (lo=bf16(lo), hi=bf16(hi)); round-half-up, 3 VALU.
__device__ __forceinline__ unsigned int pk2(float lo, float hi){
  union { float f; unsigned int i; } a, b; a.f = lo; b.f = hi;
  return __builtin_amdgcn_perm(b.i + 0x8000u, a.i + 0x8000u, 0x07060302u);
}
__device__ __forceinline__ float sigm(float x){ return 1.f/(1.f+__expf(-x)); }
__device__ __forceinline__ float tanh_f(float x){ float e = __expf(2.f*x); return 1.f - 2.f/(e+1.f); }
// LDS swizzle: 8-element (16B) chunks, phys chunk = (c&24) | ((c^row)&7).
__device__ __forceinline__ int xsw(int row, int n){
  int c = n >> 3;
  int pc = (c & 24) | ((c ^ row) & 7);
  return row*256 + pc*8 + (n & 7);
}

#define MFMA16(a,b,c) __builtin_amdgcn_mfma_f32_16x16x32_bf16((a),(b),(c),0,0,0)

// ---------------- K0: repack of 7 weight blocks + wmean, FUSED with prep ----------------
__global__ __launch_bounds__(256) void k_reprep(const float* __restrict__ Wih,
                                                const float* __restrict__ Whh,
                                                const float* __restrict__ Wgr,
                                                const float* __restrict__ Wbc,
                                                const float* __restrict__ Wesa,
                                                const float* __restrict__ Wmu,
                                                unsigned short* __restrict__ wcv,
                                                float* __restrict__ wmean,
                                                const float* __restrict__ emb,
                                                const int* __restrict__ counts,
                                                unsigned short* __restrict__ olf,
                                                float* __restrict__ out){
  if (blockIdx.x >= 3329){
    // prep part: olf0 = emb * mask (f32 -> bf16) + zero out
    int bs = blockIdx.x - 3329;     // b*28+s, 0..7167
    int b = bs / 28; int s = bs - b*28;
    int e = threadIdx.x;
    olf[(size_t)bs*256 + e] = (s < counts[b]) ? f2b(emb[(size_t)bs*256 + e]) : (unsigned short)0;
    out[(size_t)bs*256 + e] = 0.f;
    return;
  }
  int i = blockIdx.x*256 + threadIdx.x;
  if (i >= 851968){                      // tail: wmean
    int o = i - 851968;
    if (o < 256) wmean[o] = (Wmu[o] + Wmu[256+o] + Wmu[512+o]) * (1.f/3.f);
    return;
  }
  const float* s; int segbase, N, stride, off, local;
  if      (i < 262144){ s=Wih;  segbase=0;      N=1024; stride=256; off=0;   local=i; }
  else if (i < 524288){ s=Whh;  segbase=262144; N=1024; stride=256; off=0;   local=i-262144; }
  else if (i < 589824){ s=Wgr;  segbase=524288; N=256;  stride=768; off=0;   local=i-524288; }
  else if (i < 655360){ s=Wgr;  segbase=589824; N=256;  stride=768; off=256; local=i-589824; }
  else if (i < 720896){ s=Wgr;  segbase=655360; N=256;  stride=768; off=512; local=i-655360; }
  else if (i < 786432){ s=Wbc;  segbase=720896; N=256;  stride=256; off=0;   local=i-720896; }
  else                { s=Wesa; segbase=786432; N=256;  stride=256; off=0;   local=i-786432; }
  int n = local >> 8, k = local & 255;
  wcv[segbase + (((k >> 3)*N + n) << 3) + (k & 7)] = f2b(s[n*stride + off + k]);
}

// ---------------- K2a: zx = olf_l @ Wih^T  [7168,256]@[256,1024] -> bf16 ----------------
// Transposed store side (verified R24/R27): lane holds zx[m0+col][nt*16+quad*4..+3].
__global__ __launch_bounds__(256) void k_xgemm(const unsigned short* __restrict__ olf,
                                               const unsigned short* __restrict__ Wih,
                                               unsigned short* __restrict__ zx){
  const int tid = threadIdx.x;
  const int wid = tid >> 6, lane = tid & 63, col = lane & 15, quad = lane >> 4;
  const int m0 = (blockIdx.x >> 1)*64 + wid*16;
  const int nt0 = (blockIdx.x & 1)*32;
  short8 af[8];
  #pragma unroll
  for (int kt=0; kt<8; ++kt)
    af[kt] = *(const short8*)&olf[(size_t)(m0 + col)*256 + kt*32 + quad*8];
  #pragma unroll 4
  for (int nt=nt0; nt<nt0+32; ++nt){
    int n = nt*16 + col;
    f32x4 acc = (f32x4){0.f,0.f,0.f,0.f};
    #pragma unroll
    for (int kt=0; kt<8; ++kt){
      short8 bf = *(const short8*)&Wih[((((kt*4 + quad) << 10) + n) << 3)];
      acc = MFMA16(bf, af[kt], acc);
    }
    *(uint2*)&zx[(size_t)(m0 + col)*1024 + nt*16 + quad*4] =
        make_uint2(pk2(acc[0],acc[1]), pk2(acc[2],acc[3]));
  }
}

// ---------------- K2b: FUSED recurrence + A-terms (i-half gets +bgr folded) ----------------
// rec branch: Whh kt 0..1 in LDS (128KB, filled once), kt 2..4 in registers
// (48 VGPR/thread, loaded once), kt 5..7 streamed from L2 each step.
__global__ __launch_bounds__(1024) void k_recat(const unsigned short* __restrict__ zx,
                                                const unsigned short* __restrict__ Whh,
                                                const float* __restrict__ bih,
                                                const float* __restrict__ bhh,
                                                const int* __restrict__ counts,
                                                unsigned short* __restrict__ olf_out,
                                                const unsigned short* __restrict__ olf_at,
                                                const unsigned short* __restrict__ Wgri,
                                                const unsigned short* __restrict__ Wgrj,
                                                const float* __restrict__ bgr,
                                                unsigned short* __restrict__ At_out){
  __shared__ unsigned short Ab[2][16*264];   // used by rec blocks only
  __shared__ unsigned short Wlds[8192*8];    // Whh chunks c in [0,8192) == kt 0..1 (128 KB)
  const int tid = threadIdx.x;
  const int wv = tid >> 6, lane = tid & 63, col = lane & 15, quad = lane >> 4;

  if (blockIdx.x >= 16){
    // ---- aterm part: 16 waves x 16 rows, transposed store side (R27) ----
    const int m0 = (blockIdx.x - 16)*256 + wv*16;
    short8 af[8];
    #pragma unroll
    for (int kt=0; kt<8; ++kt)
      af[kt] = *(const short8*)&olf_at[(size_t)(m0 + col)*256 + kt*32 + quad*8];
    #pragma unroll 4
    for (int nt=0; nt<32; ++nt){
      const unsigned short* wb = (nt < 16) ? Wgri : Wgrj;
      int nb = (nt < 16) ? 0 : 256;
      int nn = (nt & 15)*16 + col;
      f32x4 bg4 = (nt < 16) ? *(const f32x4*)&bgr[(nt & 15)*16 + quad*4]
                            : (f32x4){0.f,0.f,0.f,0.f};
      f32x4 acc = (f32x4){0.f,0.f,0.f,0.f};
      #pragma unroll
      for (int kt=0; kt<8; ++kt){
        short8 bf = *(const short8*)&wb[((((kt*4 + quad) << 8) + nn) << 3)];
        acc = MFMA16(bf, af[kt], acc);
      }
      acc += bg4;
      *(uint2*)&At_out[(size_t)(m0 + col)*512 + nb + (nt & 15)*16 + quad*4] =
          make_uint2(pk2(acc[0],acc[1]), pk2(acc[2],acc[3]));
    }
    return;
  }
  // ---- recurrence part (R31 body + register weight cache kt 2..4) ----
  const int sc0 = blockIdx.x * 16;
  const int u = wv*16 + col;
  float bz[4];
  #pragma unroll
  for (int g=0; g<4; ++g) bz[g] = bih[g*256+u] + bhh[g*256+u];
  int cnt4[4];
  #pragma unroll
  for (int r=0; r<4; ++r) cnt4[r] = counts[sc0 + quad*4 + r];

  float cst[4];
  #pragma unroll
  for (int r=0; r<4; ++r) cst[r] = 0.f;
  for (int i=tid; i<16*264; i+=1024) Ab[0][i] = 0;   // h0 = 0
  // one-time Whh kt<2 slice -> LDS (8192 chunks x 16B = 128 KB)
  for (int c = tid; c < 8192; c += 1024)
    *(uint4*)&Wlds[c << 3] = *(const uint4*)&Whh[c << 3];
  // one-time Whh kt=2..4 -> persistent registers (48 VGPR/thread)
  short8 wreg[3][4];
  #pragma unroll
  for (int kk=0; kk<3; ++kk){
    #pragma unroll
    for (int g=0; g<4; ++g)
      wreg[kk][g] = *(const short8*)&Whh[((((kk+2)*4 + quad) << 10) + g*256 + u) << 3];
  }
  __syncthreads();

  for (int t=0; t<28; ++t){
    const int cur = t & 1, nxt = cur ^ 1;
    float zxv[4][4];
    #pragma unroll
    for (int g=0; g<4; ++g){
      #pragma unroll
      for (int r=0; r<4; ++r)
        zxv[g][r] = b2f(zx[((size_t)(sc0 + quad*4 + r)*28 + t)*1024 + g*256 + u]);
    }
    f32x4 acc[4];
    #pragma unroll
    for (int g=0; g<4; ++g) acc[g] = (f32x4){0.f,0.f,0.f,0.f};
    #pragma unroll
    for (int kt=0; kt<8; ++kt){
      short8 a = *(const short8*)&Ab[cur][col*264 + kt*32 + quad*8];
      #pragma unroll
      for (int g=0; g<4; ++g){
        int cidx = (((kt*4 + quad) << 10) + g*256 + u);
        short8 bf = (kt < 2) ? *(const short8*)&Wlds[cidx << 3]
                  : (kt < 5) ? wreg[kt-2][g]
                             : *(const short8*)&Whh[cidx << 3];
        acc[g] = MFMA16(a, bf, acc[g]);
      }
    }
    // no barrier: writes go to Ab[nxt], readers used Ab[cur]
    #pragma unroll
    for (int r=0; r<4; ++r){
      int s = quad*4 + r;
      float zi = acc[0][r] + zxv[0][r] + bz[0];
      float zf = acc[1][r] + zxv[1][r] + bz[1];
      float zg = acc[2][r] + zxv[2][r] + bz[2];
      float zo = acc[3][r] + zxv[3][r] + bz[3];
      float cc = sigm(zf)*cst[r] + sigm(zi)*tanh_f(zg);
      cst[r] = cc;
      float hh = sigm(zo)*tanh_f(cc);
      unsigned short hb = f2b(hh);
      Ab[nxt][s*264 + u] = hb;                              // raw h feeds recurrence
      olf_out[((size_t)(sc0+s)*28 + t)*256 + u] = (t < cnt4[r]) ? hb : (unsigned short)0;
    }
    __syncthreads();   // Ab[nxt] complete before step t+1 reads it
  }
}

// ---------------- K3: A-terms for ONE layer, transposed store side ----------------
__global__ __launch_bounds__(256) void k_aterm(const unsigned short* __restrict__ olf,
                                               const unsigned short* __restrict__ Wgri,
                                               const unsigned short* __restrict__ Wgrj,
                                               const float* __restrict__ bgr,
                                               unsigned short* __restrict__ Aout){
  const int tid = threadIdx.x;
  const int wid = tid >> 6, lane = tid & 63, col = lane & 15, quad = lane >> 4;
  const int m0 = blockIdx.x*64 + wid*16;
  short8 af[8];
  #pragma unroll
  for (int kt=0; kt<8; ++kt)
    af[kt] = *(const short8*)&olf[(size_t)(m0 + col)*256 + kt*32 + quad*8];
  #pragma unroll 4
  for (int nt=0; nt<32; ++nt){
    const unsigned short* wb = (nt < 16) ? Wgri : Wgrj;
    int nb = (nt < 16) ? 0 : 256;
    int nn = (nt & 15)*16 + col;
    f32x4 bg4 = (nt < 16) ? *(const f32x4*)&bgr[(nt & 15)*16 + quad*4]
                          : (f32x4){0.f,0.f,0.f,0.f};
    f32x4 acc = (f32x4){0.f,0.f,0.f,0.f};
    #pragma unroll
    for (int kt=0; kt<8; ++kt){
      short8 bf = *(const short8*)&wb[((((kt*4 + quad) << 8) + nn) << 3)];
      acc = MFMA16(bf, af[kt], acc);
    }
    acc += bg4;
    *(uint2*)&Aout[(size_t)(m0 + col)*512 + nb + (nt & 15)*16 + quad*4] =
        make_uint2(pk2(acc[0],acc[1]), pk2(acc[2],acc[3]));
  }
}

// ---------------- K4: fused per-(scene, j-pair), transposed-output GEMMs ----------------
#define GEMM_TILE64(SRC, WPTR)                                                      \
  {                                                                                 \
    _Pragma("unroll")                                                               \
    for (int rf=0; rf<4; ++rf){ Ya[rf][0]=(f32x4){0.f,0.f,0.f,0.f};                 \
                                Ya[rf][1]=(f32x4){0.f,0.f,0.f,0.f}; }               \
    _Pragma("unroll 1")                                                             \
    for (int kc=0; kc<4; ++kc){                                                     \
      short8 av[2][4], bv[2][2];                                                    \
      _Pragma("unroll")                                                             \
      for (int u=0; u<2; ++u){                                                      \
        int kt = kc*2 + u;                                                          \
        _Pragma("unroll")                                                           \
        for (int rf=0; rf<4; ++rf)                                                  \
          av[u][rf] = *(const short8*)&(SRC)[(Abase[rf] + kc*64) ^ (u*32)];         \
        bv[u][0] = *(const short8*)&(WPTR)[Bbase + kt*8192];                        \
        bv[u][1] = *(const short8*)&(WPTR)[Bbase + kt*8192 + 128];                  \
      }                                                                             \
      __builtin_amdgcn_s_setprio(1);                                                \
      _Pragma("unroll")                                                             \
      for (int u=0; u<2; ++u){                                                      \
        _Pragma("unroll")                                                           \
        for (int rf=0; rf<4; ++rf){                                                 \
          Ya[rf][0] = MFMA16(bv[u][0], av[u][rf], Ya[rf][0]);                       \
          Ya[rf][1] = MFMA16(bv[u][1], av[u][rf], Ya[rf][1]);                       \
        }                                                                           \
      }                                                                             \
      __builtin_amdgcn_s_setprio(0);                                                \
    }                                                                               \
  }

__global__ __launch_bounds__(512, 4) void k_mega(
    const float* __restrict__ centers, const int* __restrict__ counts,
    const float* __restrict__ Wr, const float* __restrict__ br,
    const unsigned short* __restrict__ Wgrr, const float* __restrict__ bgr,
    const unsigned short* __restrict__ Wbc, const float* __restrict__ bbc,
    const float* __restrict__ alpha,
    const unsigned short* __restrict__ Wesa, const float* __restrict__ besa,
    const float* __restrict__ wmean, const float* __restrict__ bmu,
    const unsigned short* __restrict__ Aterm, float* __restrict__ out){
  __shared__ unsigned short Xa[64*256];    // rlf -> E=exp(resa); rows 56..63 pad/stats
  __shared__ unsigned short Yb[64*256];    // rlf_lin / resa
  float* hrSBp = (float*)&Xa[56*256];      // 512 f32 [jc*256+o]: 0.5/sum_i E
  float* gsbp  = (float*)&Xa[60*256];      // 64 f32 per row p: G = exp(gscore)
  float* hrSGp = (float*)&Xa[60*256+128];  // 2 f32 per jc: 0.5/sum_i G
  const int tid = threadIdx.x;
  const int wv = tid >> 6;          // 0..7 -> col slice
  const int lane = tid & 63, col = lane & 15, quad = lane >> 4;
  // XCD-aware swizzle: all 14 jt-blocks of scene b land on the same XCD
  const int xcd = blockIdx.x & 7, idx = blockIdx.x >> 3;   // idx 0..447
  const int b = xcd*32 + idx/14, jt = idx - (idx/14)*14;   // j = jt*2 + jc
  const int cb = counts[b];
  const int nbase = wv*32;

  float av_ = alpha[0];
  float tv = sigm(av_);
  float c1 = (1.f-tv)*(1.f-tv) + tv*tv;
  float c2 = 2.f*tv*(1.f-tv);

  // per-thread row mapping for transposed fragments: m = mt*16 + col
  float pv[4];
  const unsigned short* apI[4];
  const unsigned short* apJ[4];
  #pragma unroll
  for (int mt=0; mt<4; ++mt){
    int m = mt*16 + col;
    int i = m >> 1;
    int pi = (i < 27) ? i : 27;
    int pj = jt*2 + (m & 1);
    pv[mt] = (m < 56 && i < cb && pj < cb) ? 1.f : 0.f;
    apI[mt] = Aterm + (size_t)(b*28 + pi)*512 + nbase + quad*4;
    apJ[mt] = Aterm + (size_t)(b*28 + pj)*512 + 256 + nbase + quad*4;
  }
  // hoisted swizzled addresses (reused across all 7 GEMMs / 3 layers)
  int Abase[4];
  #pragma unroll
  for (int rf=0; rf<4; ++rf){
    int row = rf*16 + col;
    Abase[rf] = row*256 + ((quad ^ (row & 3)) | (row & 4))*8;
  }
  const int Bbase = (quad*256 + nbase + col)*8;
  int woff[4][2];
  f32x4 cbb[2], bev[2];
  #pragma unroll
  for (int nt2=0; nt2<2; ++nt2){
    int n0 = nbase + nt2*16 + quad*4;
    cbb[nt2] = (*(const f32x4*)&bbc[n0]) * c2;   // c2*bbc hoisted for S4
    bev[nt2] = *(const f32x4*)&besa[n0];
    #pragma unroll
    for (int mt=0; mt<4; ++mt)
      woff[mt][nt2] = xsw(mt*16 + col, n0);
  }

  // S0: rlf0[row] -> Xa ; pad rows = 0. Vectorized: float4 Wr/br, uint4 writes.
  {
    int m = tid >> 3, sub = tid & 7;   // m 0..63, 32 cols each
    int i = m >> 1, j = jt*2 + (m & 1);
    bool valid = (m < 56);
    float mi = (valid && i < cb) ? 1.f : 0.f;
    float mj = (valid && j < cb) ? 1.f : 0.f;
    float vm = valid ? 1.f : 0.f;
    const float* ci = centers + (b*28 + (valid ? i : 0))*3;
    const float* cj = centers + (b*28 + j)*3;
    float dx = mi*ci[0] - mj*cj[0];
    float dy = mi*ci[1] - mj*cj[1];
    float dz = mi*ci[2] - mj*cj[2];
    #pragma unroll
    for (int c8=0; c8<4; ++c8){
      int e0 = sub*32 + c8*8;
      f32x4 w0 = *(const f32x4*)&Wr[e0*3 +  0];
      f32x4 w1 = *(const f32x4*)&Wr[e0*3 +  4];
      f32x4 w2 = *(const f32x4*)&Wr[e0*3 +  8];
      f32x4 w3 = *(const f32x4*)&Wr[e0*3 + 12];
      f32x4 w4 = *(const f32x4*)&Wr[e0*3 + 16];
      f32x4 w5 = *(const f32x4*)&Wr[e0*3 + 20];
      f32x4 b0 = *(const f32x4*)&br[e0];
      f32x4 b1 = *(const f32x4*)&br[e0+4];
      b0 *= vm; b1 *= vm;   // invalid rows: dx=dy=dz=0 and b=0 -> v=0
      float v0 = dx*w0[0] + dy*w0[1] + dz*w0[2] + b0[0];
      float v1 = dx*w0[3] + dy*w1[0] + dz*w1[1] + b0[1];
      float v2 = dx*w1[2] + dy*w1[3] + dz*w2[0] + b0[2];
      float v3 = dx*w2[1] + dy*w2[2] + dz*w2[3] + b0[3];
      float v4 = dx*w3[0] + dy*w3[1] + dz*w3[2] + b1[0];
      float v5 = dx*w3[3] + dy*w4[0] + dz*w4[1] + b1[1];
      float v6 = dx*w4[2] + dy*w4[3] + dz*w5[0] + b1[2];
      float v7 = dx*w5[1] + dy*w5[2] + dz*w5[3] + b1[3];
      uint4 pw;
      pw.x = pk2(v0,v1); pw.y = pk2(v2,v3); pw.z = pk2(v4,v5); pw.w = pk2(v6,v7);
      *(uint4*)&Xa[xsw(m, e0)] = pw;
    }
  }
  __syncthreads();

  f32x4 Ya[4][2];
  #pragma unroll 1
  for (int l=0; l<3; ++l){
    // At PREFETCH for this layer's S2 -- issued BEFORE GEMM1 (independent of Xa).
    uint2 rAi[4][2], rAj[4][2];
    #pragma unroll
    for (int mt=0; mt<4; ++mt){
      rAi[mt][0] = *(const uint2*)&apI[mt][0];
      rAi[mt][1] = *(const uint2*)&apI[mt][16];
      rAj[mt][0] = *(const uint2*)&apJ[mt][0];
      rAj[mt][1] = *(const uint2*)&apJ[mt][16];
      apI[mt] += 7168*512; apJ[mt] += 7168*512;
    }
    // GEMM1: Wgr_r x rlf(Xa)^T -- then S2 writes Yb (no barrier in between)
    GEMM_TILE64(Xa, Wgrr);
    // S2: rlf_lin = Y + (Ai+bgr) + Aj -> Yb (vector adds + 8B packed writes)
    #pragma unroll
    for (int nt2=0; nt2<2; ++nt2){
      #pragma unroll
      for (int mt=0; mt<4; ++mt){
        uint2 wi = rAi[mt][nt2], wj = rAj[mt][nt2];
        f32x4 ai, aj;
        ai[0] = u2f(wi.x << 16); ai[1] = u2f(wi.x & 0xffff0000u);
        ai[2] = u2f(wi.y << 16); ai[3] = u2f(wi.y & 0xffff0000u);
        aj[0] = u2f(wj.x << 16); aj[1] = u2f(wj.x & 0xffff0000u);
        aj[2] = u2f(wj.y << 16); aj[3] = u2f(wj.y & 0xffff0000u);
        f32x4 v = Ya[mt][nt2] + ai + aj;
        *(uint2*)&Yb[woff[mt][nt2]] = make_uint2(pk2(v[0],v[1]), pk2(v[2],v[3]));
      }
    }
    __syncthreads();   // Yb complete before GEMM2 reads it
    // GEMM2: Wbc x rlf_lin(Yb)^T -- then S4 writes Xa (no barrier in between)
    GEMM_TILE64(Yb, Wbc);
    // S4: rlf = tanh(rl*c1 + (Ya*c2 + cbb)) * pv -> Xa
    #pragma unroll
    for (int nt2=0; nt2<2; ++nt2){
      #pragma unroll
      for (int mt=0; mt<4; ++mt){
        uint2 w = *(const uint2*)&Yb[woff[mt][nt2]];
        f32x4 rl;
        rl[0] = u2f(w.x << 16); rl[1] = u2f(w.x & 0xffff0000u);
        rl[2] = u2f(w.y << 16); rl[3] = u2f(w.y & 0xffff0000u);
        f32x4 bez = Ya[mt][nt2]*c2 + cbb[nt2];
        bez = rl*c1 + bez;
        float x0 = tanh_f(bez[0]) * pv[mt];
        float x1 = tanh_f(bez[1]) * pv[mt];
        float x2 = tanh_f(bez[2]) * pv[mt];
        float x3 = tanh_f(bez[3]) * pv[mt];
        *(uint2*)&Xa[woff[mt][nt2]] = make_uint2(pk2(x0,x1), pk2(x2,x3));
      }
    }
    __syncthreads();   // Xa complete before next GEMM1; fences Yb readers vs next S2
  }
  // S5: resa = Wesa x rlf(Xa)^T + besa -> v to Yb, E=exp(v) to Xa,
  // and in-register SB column partial sums (unrounded E).
  GEMM_TILE64(Xa, Wesa);
  __syncthreads();   // all GEMM reads of Xa(rlf) done before E overwrites it
  f32x4 sbp[2] = {(f32x4){0.f,0.f,0.f,0.f}, (f32x4){0.f,0.f,0.f,0.f}};
  const float m3f = (col < 8) ? 1.f : 0.f;   // mt=3 rows 48+col: valid iff col<8
  #pragma unroll
  for (int nt2=0; nt2<2; ++nt2){
    #pragma unroll
    for (int mt=0; mt<4; ++mt){
      f32x4 v = Ya[mt][nt2] + bev[nt2];
      *(uint2*)&Yb[woff[mt][nt2]] = make_uint2(pk2(v[0],v[1]), pk2(v[2],v[3]));
      f32x4 e;
      e[0] = __expf(v[0]); e[1] = __expf(v[1]);
      e[2] = __expf(v[2]); e[3] = __expf(v[3]);
      *(uint2*)&Xa[woff[mt][nt2]] = make_uint2(pk2(e[0],e[1]), pk2(e[2],e[3]));
      f32x4 wsum = e;
      if (mt == 3) wsum *= m3f;
      sbp[nt2] += wsum;
    }
  }
  // reduce across the 8 same-parity lanes of this quad (col strides 2,4,8)
  f32x4 hr[2];
  #pragma unroll
  for (int nt2=0; nt2<2; ++nt2){
    #pragma unroll
    for (int r=0; r<4; ++r){
      float s = sbp[nt2][r];
      s += __shfl_xor(s, 2, 64);
      s += __shfl_xor(s, 4, 64);
      s += __shfl_xor(s, 8, 64);
      hr[nt2][r] = 0.5f / s;
    }
  }
  __syncthreads();
  // G[row] = exp(gscore) (reads Yb, uint4 + wmean float4); hrSBp stores (col<2)
  {
    int m = tid >> 3, sub = tid & 7;   // 8 threads per row, 32 cols each
    if (m < 56){
      float s = 0.f;
      #pragma unroll
      for (int c8=0; c8<4; ++c8){
        int e0 = sub*32 + c8*8;
        uint4 u = *(const uint4*)&Yb[xsw(m, e0)];
        f32x4 wm0 = *(const f32x4*)&wmean[e0];
        f32x4 wm1 = *(const f32x4*)&wmean[e0+4];
        s += u2f(u.x << 16)*wm0[0] + u2f(u.x & 0xffff0000u)*wm0[1]
           + u2f(u.y << 16)*wm0[2] + u2f(u.y & 0xffff0000u)*wm0[3]
           + u2f(u.z << 16)*wm1[0] + u2f(u.z & 0xffff0000u)*wm1[1]
           + u2f(u.w << 16)*wm1[2] + u2f(u.w & 0xffff0000u)*wm1[3];
      }
      s += __shfl_xor(s, 1, 64);
      s += __shfl_xor(s, 2, 64);
      s += __shfl_xor(s, 4, 64);
      if (sub == 0)
        gsbp[m] = __expf(s + (bmu[0] + bmu[1] + bmu[2])*(1.f/3.f));
    }
  }
  if (col < 2){   // jc = col; every parity lane holds the full parity sum
    #pragma unroll
    for (int nt2=0; nt2<2; ++nt2){
      #pragma unroll
      for (int r=0; r<4; ++r)
        hrSBp[col*256 + nbase + nt2*16 + quad*4 + r] = hr[nt2][r];
    }
  }
  __syncthreads();
  // hrSGp: single-wave butterfly over gsbp[0..55] (was 2-thread 28-iter loop)
  if (tid < 64){
    float g = (tid < 56) ? gsbp[tid] : 0.f;
    g += __shfl_xor(g, 2, 64);
    g += __shfl_xor(g, 4, 64);
    g += __shfl_xor(g, 8, 64);
    g += __shfl_xor(g, 16, 64);
    g += __shfl_xor(g, 32, 64);
    if (tid < 2) hrSGp[tid] = 0.5f / g;   // tid==jc: sum over same-parity rows
  }
  __syncthreads();
  // masked output: scalar-contiguous atomics (R25 form; 64 lanes cover 256B)
  for (int it = tid; it < 7168; it += 512){
    int i = it >> 8, o = it & 255;
    if (i < cb){
      float s = 0.f;
      #pragma unroll
      for (int jc=0; jc<2; ++jc){
        int row = i*2 + jc;
        int off = xsw(row, o);
        float v = b2f(Yb[off]);
        float E = b2f(Xa[off]);
        float a = E*hrSBp[jc*256+o] + gsbp[row]*hrSGp[jc];
        s += a * v;
      }
      atomicAdd(&out[((size_t)b*28 + i)*256 + o], s);
    }
  }
}

extern "C" void kernel_launch(void* const* d_in, const int* in_sizes, int n_in,
                              void* d_out, int out_size, void* d_ws, size_t ws_size,
                              hipStream_t stream){
  const float* centers = (const float*)d_in[0];
  const float* emb     = (const float*)d_in[1];
  const int*   counts  = (const int*)d_in[2];
  const float* Wr      = (const float*)d_in[3];
  const float* br      = (const float*)d_in[4];
  const float* Wih     = (const float*)d_in[5];
  const float* Whh     = (const float*)d_in[6];
  const float* bih     = (const float*)d_in[7];
  const float* bhh     = (const float*)d_in[8];
  const float* Wgr     = (const float*)d_in[9];
  const float* bgr     = (const float*)d_in[10];
  const float* Wbc     = (const float*)d_in[11];
  const float* bbc     = (const float*)d_in[12];
  const float* alpha   = (const float*)d_in[13];
  const float* Wesa    = (const float*)d_in[14];
  const float* besa    = (const float*)d_in[15];
  const float* Wmu     = (const float*)d_in[16];
  const float* bmu     = (const float*)d_in[17];
  // d_in[18], d_in[19] (Wlv, blv) are dead at eval time.

  // ws layout (49,415,168 bytes total):
  unsigned short* olf   = (unsigned short*)d_ws;                      // 3*7168*256 bf16
  unsigned short* At    = (unsigned short*)((char*)d_ws + 11010048);  // 3*7168*512 bf16
  unsigned short* zx    = (unsigned short*)((char*)d_ws + 33030144);  // 7168*1024 bf16
  unsigned short* wcv   = (unsigned short*)((char*)d_ws + 47710208);  // 851,968 bf16
  float*          wmean = (float*)((char*)d_ws + 49414144);           // 256 f32
  unsigned short* cWih  = wcv;            // 262144 (N=1024)
  unsigned short* cWhh  = wcv + 262144;   // 262144 (N=1024)
  unsigned short* cWgri = wcv + 524288;   // 65536  (N=256)
  unsigned short* cWgrj = wcv + 589824;   // 65536  (N=256)
  unsigned short* cWgrr = wcv + 655360;   // 65536  (N=256)
  unsigned short* cWbc  = wcv + 720896;   // 65536  (N=256)
  unsigned short* cWesa = wcv + 786432;   // 65536  (N=256)
  float* outp = (float*)d_out;

  unsigned short* olf1 = olf + (size_t)7168*256;
  unsigned short* olf2 = olf + (size_t)2*7168*256;
  unsigned short* At1  = At  + (size_t)7168*512;
  unsigned short* At2  = At  + (size_t)2*7168*512;

  // 1) repack + prep fused
  hipLaunchKernelGGL(k_reprep, dim3(10497), dim3(256), 0, stream,
                     Wih, Whh, Wgr, Wbc, Wesa, Wmu, wcv, wmean,
                     emb, counts, olf, outp);
  // 2) LSTM pass 1 (olf0 -> olf1) fused with A-terms layer 0 (olf0 -> At0)
  hipLaunchKernelGGL(k_xgemm, dim3(224), dim3(256), 0, stream, olf, cWih, zx);
  hipLaunchKernelGGL(k_recat, dim3(44), dim3(1024), 0, stream,
                     zx, cWhh, bih, bhh, counts, olf1, olf, cWgri, cWgrj, bgr, At);
  // 3) LSTM pass 2 (olf1 -> olf2) fused with A-terms layer 1 (olf1 -> At1)
  hipLaunchKernelGGL(k_xgemm, dim3(224), dim3(256), 0, stream, olf1, cWih, zx);
  hipLaunchKernelGGL(k_recat, dim3(44), dim3(1024), 0, stream,
                     zx, cWhh, bih, bhh, counts, olf2, olf1, cWgri, cWgrj, bgr, At1);
  // 4) A-terms layer 2 (olf2 -> At2)
  hipLaunchKernelGGL(k_aterm, dim3(112), dim3(256), 0, stream, olf2, cWgri, cWgrj, bgr, At2);
  // 5) fused relation/attention/output
  hipLaunchKernelGGL(k_mega,  dim3(3584), dim3(512), 0, stream,
                     centers, counts, Wr, br, cWgrr, bgr, cWbc, bbc, alpha,
                     cWesa, besa, wmean, bmu, At, outp);
}

// Round 13
// 1039.478 us; speedup vs baseline: 1.0015x; 1.0015x over previous
//
#include <hip/hip_runtime.h>

// ObjectMsgEncoder on MI355X. f32 I/O, bf16 MFMA internally (f32 accumulate).
// R32 -> R33: spill-avoidance retry of the register weight cache. R32's 48
// wreg VGPRs exceeded the 128-VGPR cap implied by launch_bounds(1024) (16
// waves/block = 4 waves/SIMD) -> scratch spill -> re-read 192KB/step from
// scratch, exactly cancelling the L2 traffic saved (observed +10us/launch).
// R33 holds only kt 2..3 in registers (32 VGPR, total ~96-112 < 128): LDS has
// kt 0..1 (128KB, R31-verified -25%/launch), registers kt 2..3, L2 streams
// kt 4..7 (256KB/step, was 384KB). kt is compile-time -> static selection.
// Weights bit-identical -> numerics unchanged. Everything else byte-identical
// to R31 (best: 1019.5us; k_mega 478-483 VALU-bound).

typedef __attribute__((ext_vector_type(8))) short short8;
typedef __attribute__((ext_vector_type(4))) float f32x4;

__device__ __forceinline__ float b2f(unsigned short u){
  union { unsigned int i; float f; } v; v.i = ((unsigned int)u) << 16; return v.f;
}
__device__ __forceinline__ float u2f(unsigned int u){
  union { unsigned int i; float f; } v; v.i = u; return v.f;
}
__device__ __forceinline__ unsigned short f2b(float f){
  union { float f; unsigned int i; } v; v.f = f;
  return (unsigned short)((v.i + 0x8000u) >> 16);   // round-half-up
}
// pack two f32 -> bf16x2 (lo=bf16(lo), hi=bf16(hi)); round-half-up, 3 VALU.
__device__ __forceinline__ unsigned int pk2(float lo, float hi){
  union { float f; unsigned int i; } a, b; a.f = lo; b.f = hi;
  return __builtin_amdgcn_perm(b.i + 0x8000u, a.i + 0x8000u, 0x07060302u);
}
__device__ __forceinline__ float sigm(float x){ return 1.f/(1.f+__expf(-x)); }
__device__ __forceinline__ float tanh_f(float x){ float e = __expf(2.f*x); return 1.f - 2.f/(e+1.f); }
// LDS swizzle: 8-element (16B) chunks, phys chunk = (c&24) | ((c^row)&7).
__device__ __forceinline__ int xsw(int row, int n){
  int c = n >> 3;
  int pc = (c & 24) | ((c ^ row) & 7);
  return row*256 + pc*8 + (n & 7);
}

#define MFMA16(a,b,c) __builtin_amdgcn_mfma_f32_16x16x32_bf16((a),(b),(c),0,0,0)

// ---------------- K0: repack of 7 weight blocks + wmean, FUSED with prep ----------------
__global__ __launch_bounds__(256) void k_reprep(const float* __restrict__ Wih,
                                                const float* __restrict__ Whh,
                                                const float* __restrict__ Wgr,
                                                const float* __restrict__ Wbc,
                                                const float* __restrict__ Wesa,
                                                const float* __restrict__ Wmu,
                                                unsigned short* __restrict__ wcv,
                                                float* __restrict__ wmean,
                                                const float* __restrict__ emb,
                                                const int* __restrict__ counts,
                                                unsigned short* __restrict__ olf,
                                                float* __restrict__ out){
  if (blockIdx.x >= 3329){
    // prep part: olf0 = emb * mask (f32 -> bf16) + zero out
    int bs = blockIdx.x - 3329;     // b*28+s, 0..7167
    int b = bs / 28; int s = bs - b*28;
    int e = threadIdx.x;
    olf[(size_t)bs*256 + e] = (s < counts[b]) ? f2b(emb[(size_t)bs*256 + e]) : (unsigned short)0;
    out[(size_t)bs*256 + e] = 0.f;
    return;
  }
  int i = blockIdx.x*256 + threadIdx.x;
  if (i >= 851968){                      // tail: wmean
    int o = i - 851968;
    if (o < 256) wmean[o] = (Wmu[o] + Wmu[256+o] + Wmu[512+o]) * (1.f/3.f);
    return;
  }
  const float* s; int segbase, N, stride, off, local;
  if      (i < 262144){ s=Wih;  segbase=0;      N=1024; stride=256; off=0;   local=i; }
  else if (i < 524288){ s=Whh;  segbase=262144; N=1024; stride=256; off=0;   local=i-262144; }
  else if (i < 589824){ s=Wgr;  segbase=524288; N=256;  stride=768; off=0;   local=i-524288; }
  else if (i < 655360){ s=Wgr;  segbase=589824; N=256;  stride=768; off=256; local=i-589824; }
  else if (i < 720896){ s=Wgr;  segbase=655360; N=256;  stride=768; off=512; local=i-655360; }
  else if (i < 786432){ s=Wbc;  segbase=720896; N=256;  stride=256; off=0;   local=i-720896; }
  else                { s=Wesa; segbase=786432; N=256;  stride=256; off=0;   local=i-786432; }
  int n = local >> 8, k = local & 255;
  wcv[segbase + (((k >> 3)*N + n) << 3) + (k & 7)] = f2b(s[n*stride + off + k]);
}

// ---------------- K2a: zx = olf_l @ Wih^T  [7168,256]@[256,1024] -> bf16 ----------------
// Transposed store side (verified R24/R27): lane holds zx[m0+col][nt*16+quad*4..+3].
__global__ __launch_bounds__(256) void k_xgemm(const unsigned short* __restrict__ olf,
                                               const unsigned short* __restrict__ Wih,
                                               unsigned short* __restrict__ zx){
  const int tid = threadIdx.x;
  const int wid = tid >> 6, lane = tid & 63, col = lane & 15, quad = lane >> 4;
  const int m0 = (blockIdx.x >> 1)*64 + wid*16;
  const int nt0 = (blockIdx.x & 1)*32;
  short8 af[8];
  #pragma unroll
  for (int kt=0; kt<8; ++kt)
    af[kt] = *(const short8*)&olf[(size_t)(m0 + col)*256 + kt*32 + quad*8];
  #pragma unroll 4
  for (int nt=nt0; nt<nt0+32; ++nt){
    int n = nt*16 + col;
    f32x4 acc = (f32x4){0.f,0.f,0.f,0.f};
    #pragma unroll
    for (int kt=0; kt<8; ++kt){
      short8 bf = *(const short8*)&Wih[((((kt*4 + quad) << 10) + n) << 3)];
      acc = MFMA16(bf, af[kt], acc);
    }
    *(uint2*)&zx[(size_t)(m0 + col)*1024 + nt*16 + quad*4] =
        make_uint2(pk2(acc[0],acc[1]), pk2(acc[2],acc[3]));
  }
}

// ---------------- K2b: FUSED recurrence + A-terms (i-half gets +bgr folded) ----------------
// rec branch: Whh kt 0..1 in LDS (128KB, filled once), kt 2..3 in registers
// (32 VGPR/thread, loaded once), kt 4..7 streamed from L2 each step.
__global__ __launch_bounds__(1024) void k_recat(const unsigned short* __restrict__ zx,
                                                const unsigned short* __restrict__ Whh,
                                                const float* __restrict__ bih,
                                                const float* __restrict__ bhh,
                                                const int* __restrict__ counts,
                                                unsigned short* __restrict__ olf_out,
                                                const unsigned short* __restrict__ olf_at,
                                                const unsigned short* __restrict__ Wgri,
                                                const unsigned short* __restrict__ Wgrj,
                                                const float* __restrict__ bgr,
                                                unsigned short* __restrict__ At_out){
  __shared__ unsigned short Ab[2][16*264];   // used by rec blocks only
  __shared__ unsigned short Wlds[8192*8];    // Whh chunks c in [0,8192) == kt 0..1 (128 KB)
  const int tid = threadIdx.x;
  const int wv = tid >> 6, lane = tid & 63, col = lane & 15, quad = lane >> 4;

  if (blockIdx.x >= 16){
    // ---- aterm part: 16 waves x 16 rows, transposed store side (R27) ----
    const int m0 = (blockIdx.x - 16)*256 + wv*16;
    short8 af[8];
    #pragma unroll
    for (int kt=0; kt<8; ++kt)
      af[kt] = *(const short8*)&olf_at[(size_t)(m0 + col)*256 + kt*32 + quad*8];
    #pragma unroll 4
    for (int nt=0; nt<32; ++nt){
      const unsigned short* wb = (nt < 16) ? Wgri : Wgrj;
      int nb = (nt < 16) ? 0 : 256;
      int nn = (nt & 15)*16 + col;
      f32x4 bg4 = (nt < 16) ? *(const f32x4*)&bgr[(nt & 15)*16 + quad*4]
                            : (f32x4){0.f,0.f,0.f,0.f};
      f32x4 acc = (f32x4){0.f,0.f,0.f,0.f};
      #pragma unroll
      for (int kt=0; kt<8; ++kt){
        short8 bf = *(const short8*)&wb[((((kt*4 + quad) << 8) + nn) << 3)];
        acc = MFMA16(bf, af[kt], acc);
      }
      acc += bg4;
      *(uint2*)&At_out[(size_t)(m0 + col)*512 + nb + (nt & 15)*16 + quad*4] =
          make_uint2(pk2(acc[0],acc[1]), pk2(acc[2],acc[3]));
    }
    return;
  }
  // ---- recurrence part (R31 body + register weight cache kt 2..3) ----
  const int sc0 = blockIdx.x * 16;
  const int u = wv*16 + col;
  float bz[4];
  #pragma unroll
  for (int g=0; g<4; ++g) bz[g] = bih[g*256+u] + bhh[g*256+u];
  int cnt4[4];
  #pragma unroll
  for (int r=0; r<4; ++r) cnt4[r] = counts[sc0 + quad*4 + r];

  float cst[4];
  #pragma unroll
  for (int r=0; r<4; ++r) cst[r] = 0.f;
  for (int i=tid; i<16*264; i+=1024) Ab[0][i] = 0;   // h0 = 0
  // one-time Whh kt<2 slice -> LDS (8192 chunks x 16B = 128 KB)
  for (int c = tid; c < 8192; c += 1024)
    *(uint4*)&Wlds[c << 3] = *(const uint4*)&Whh[c << 3];
  // one-time Whh kt=2..3 -> persistent registers (32 VGPR/thread)
  short8 wreg[2][4];
  #pragma unroll
  for (int kk=0; kk<2; ++kk){
    #pragma unroll
    for (int g=0; g<4; ++g)
      wreg[kk][g] = *(const short8*)&Whh[((((kk+2)*4 + quad) << 10) + g*256 + u) << 3];
  }
  __syncthreads();

  for (int t=0; t<28; ++t){
    const int cur = t & 1, nxt = cur ^ 1;
    float zxv[4][4];
    #pragma unroll
    for (int g=0; g<4; ++g){
      #pragma unroll
      for (int r=0; r<4; ++r)
        zxv[g][r] = b2f(zx[((size_t)(sc0 + quad*4 + r)*28 + t)*1024 + g*256 + u]);
    }
    f32x4 acc[4];
    #pragma unroll
    for (int g=0; g<4; ++g) acc[g] = (f32x4){0.f,0.f,0.f,0.f};
    #pragma unroll
    for (int kt=0; kt<8; ++kt){
      short8 a = *(const short8*)&Ab[cur][col*264 + kt*32 + quad*8];
      #pragma unroll
      for (int g=0; g<4; ++g){
        int cidx = (((kt*4 + quad) << 10) + g*256 + u);
        short8 bf = (kt < 2) ? *(const short8*)&Wlds[cidx << 3]
                  : (kt < 4) ? wreg[kt-2][g]
                             : *(const short8*)&Whh[cidx << 3];
        acc[g] = MFMA16(a, bf, acc[g]);
      }
    }
    // no barrier: writes go to Ab[nxt], readers used Ab[cur]
    #pragma unroll
    for (int r=0; r<4; ++r){
      int s = quad*4 + r;
      float zi = acc[0][r] + zxv[0][r] + bz[0];
      float zf = acc[1][r] + zxv[1][r] + bz[1];
      float zg = acc[2][r] + zxv[2][r] + bz[2];
      float zo = acc[3][r] + zxv[3][r] + bz[3];
      float cc = sigm(zf)*cst[r] + sigm(zi)*tanh_f(zg);
      cst[r] = cc;
      float hh = sigm(zo)*tanh_f(cc);
      unsigned short hb = f2b(hh);
      Ab[nxt][s*264 + u] = hb;                              // raw h feeds recurrence
      olf_out[((size_t)(sc0+s)*28 + t)*256 + u] = (t < cnt4[r]) ? hb : (unsigned short)0;
    }
    __syncthreads();   // Ab[nxt] complete before step t+1 reads it
  }
}

// ---------------- K3: A-terms for ONE layer, transposed store side ----------------
__global__ __launch_bounds__(256) void k_aterm(const unsigned short* __restrict__ olf,
                                               const unsigned short* __restrict__ Wgri,
                                               const unsigned short* __restrict__ Wgrj,
                                               const float* __restrict__ bgr,
                                               unsigned short* __restrict__ Aout){
  const int tid = threadIdx.x;
  const int wid = tid >> 6, lane = tid & 63, col = lane & 15, quad = lane >> 4;
  const int m0 = blockIdx.x*64 + wid*16;
  short8 af[8];
  #pragma unroll
  for (int kt=0; kt<8; ++kt)
    af[kt] = *(const short8*)&olf[(size_t)(m0 + col)*256 + kt*32 + quad*8];
  #pragma unroll 4
  for (int nt=0; nt<32; ++nt){
    const unsigned short* wb = (nt < 16) ? Wgri : Wgrj;
    int nb = (nt < 16) ? 0 : 256;
    int nn = (nt & 15)*16 + col;
    f32x4 bg4 = (nt < 16) ? *(const f32x4*)&bgr[(nt & 15)*16 + quad*4]
                          : (f32x4){0.f,0.f,0.f,0.f};
    f32x4 acc = (f32x4){0.f,0.f,0.f,0.f};
    #pragma unroll
    for (int kt=0; kt<8; ++kt){
      short8 bf = *(const short8*)&wb[((((kt*4 + quad) << 8) + nn) << 3)];
      acc = MFMA16(bf, af[kt], acc);
    }
    acc += bg4;
    *(uint2*)&Aout[(size_t)(m0 + col)*512 + nb + (nt & 15)*16 + quad*4] =
        make_uint2(pk2(acc[0],acc[1]), pk2(acc[2],acc[3]));
  }
}

// ---------------- K4: fused per-(scene, j-pair), transposed-output GEMMs ----------------
#define GEMM_TILE64(SRC, WPTR)                                                      \
  {                                                                                 \
    _Pragma("unroll")                                                               \
    for (int rf=0; rf<4; ++rf){ Ya[rf][0]=(f32x4){0.f,0.f,0.f,0.f};                 \
                                Ya[rf][1]=(f32x4){0.f,0.f,0.f,0.f}; }               \
    _Pragma("unroll 1")                                                             \
    for (int kc=0; kc<4; ++kc){                                                     \
      short8 av[2][4], bv[2][2];                                                    \
      _Pragma("unroll")                                                             \
      for (int u=0; u<2; ++u){                                                      \
        int kt = kc*2 + u;                                                          \
        _Pragma("unroll")                                                           \
        for (int rf=0; rf<4; ++rf)                                                  \
          av[u][rf] = *(const short8*)&(SRC)[(Abase[rf] + kc*64) ^ (u*32)];         \
        bv[u][0] = *(const short8*)&(WPTR)[Bbase + kt*8192];                        \
        bv[u][1] = *(const short8*)&(WPTR)[Bbase + kt*8192 + 128];                  \
      }                                                                             \
      __builtin_amdgcn_s_setprio(1);                                                \
      _Pragma("unroll")                                                             \
      for (int u=0; u<2; ++u){                                                      \
        _Pragma("unroll")                                                           \
        for (int rf=0; rf<4; ++rf){                                                 \
          Ya[rf][0] = MFMA16(bv[u][0], av[u][rf], Ya[rf][0]);                       \
          Ya[rf][1] = MFMA16(bv[u][1], av[u][rf], Ya[rf][1]);                       \
        }                                                                           \
      }                                                                             \
      __builtin_amdgcn_s_setprio(0);                                                \
    }                                                                               \
  }

__global__ __launch_bounds__(512, 4) void k_mega(
    const float* __restrict__ centers, const int* __restrict__ counts,
    const float* __restrict__ Wr, const float* __restrict__ br,
    const unsigned short* __restrict__ Wgrr, const float* __restrict__ bgr,
    const unsigned short* __restrict__ Wbc, const float* __restrict__ bbc,
    const float* __restrict__ alpha,
    const unsigned short* __restrict__ Wesa, const float* __restrict__ besa,
    const float* __restrict__ wmean, const float* __restrict__ bmu,
    const unsigned short* __restrict__ Aterm, float* __restrict__ out){
  __shared__ unsigned short Xa[64*256];    // rlf -> E=exp(resa); rows 56..63 pad/stats
  __shared__ unsigned short Yb[64*256];    // rlf_lin / resa
  float* hrSBp = (float*)&Xa[56*256];      // 512 f32 [jc*256+o]: 0.5/sum_i E
  float* gsbp  = (float*)&Xa[60*256];      // 64 f32 per row p: G = exp(gscore)
  float* hrSGp = (float*)&Xa[60*256+128];  // 2 f32 per jc: 0.5/sum_i G
  const int tid = threadIdx.x;
  const int wv = tid >> 6;          // 0..7 -> col slice
  const int lane = tid & 63, col = lane & 15, quad = lane >> 4;
  // XCD-aware swizzle: all 14 jt-blocks of scene b land on the same XCD
  const int xcd = blockIdx.x & 7, idx = blockIdx.x >> 3;   // idx 0..447
  const int b = xcd*32 + idx/14, jt = idx - (idx/14)*14;   // j = jt*2 + jc
  const int cb = counts[b];
  const int nbase = wv*32;

  float av_ = alpha[0];
  float tv = sigm(av_);
  float c1 = (1.f-tv)*(1.f-tv) + tv*tv;
  float c2 = 2.f*tv*(1.f-tv);

  // per-thread row mapping for transposed fragments: m = mt*16 + col
  float pv[4];
  const unsigned short* apI[4];
  const unsigned short* apJ[4];
  #pragma unroll
  for (int mt=0; mt<4; ++mt){
    int m = mt*16 + col;
    int i = m >> 1;
    int pi = (i < 27) ? i : 27;
    int pj = jt*2 + (m & 1);
    pv[mt] = (m < 56 && i < cb && pj < cb) ? 1.f : 0.f;
    apI[mt] = Aterm + (size_t)(b*28 + pi)*512 + nbase + quad*4;
    apJ[mt] = Aterm + (size_t)(b*28 + pj)*512 + 256 + nbase + quad*4;
  }
  // hoisted swizzled addresses (reused across all 7 GEMMs / 3 layers)
  int Abase[4];
  #pragma unroll
  for (int rf=0; rf<4; ++rf){
    int row = rf*16 + col;
    Abase[rf] = row*256 + ((quad ^ (row & 3)) | (row & 4))*8;
  }
  const int Bbase = (quad*256 + nbase + col)*8;
  int woff[4][2];
  f32x4 cbb[2], bev[2];
  #pragma unroll
  for (int nt2=0; nt2<2; ++nt2){
    int n0 = nbase + nt2*16 + quad*4;
    cbb[nt2] = (*(const f32x4*)&bbc[n0]) * c2;   // c2*bbc hoisted for S4
    bev[nt2] = *(const f32x4*)&besa[n0];
    #pragma unroll
    for (int mt=0; mt<4; ++mt)
      woff[mt][nt2] = xsw(mt*16 + col, n0);
  }

  // S0: rlf0[row] -> Xa ; pad rows = 0. Vectorized: float4 Wr/br, uint4 writes.
  {
    int m = tid >> 3, sub = tid & 7;   // m 0..63, 32 cols each
    int i = m >> 1, j = jt*2 + (m & 1);
    bool valid = (m < 56);
    float mi = (valid && i < cb) ? 1.f : 0.f;
    float mj = (valid && j < cb) ? 1.f : 0.f;
    float vm = valid ? 1.f : 0.f;
    const float* ci = centers + (b*28 + (valid ? i : 0))*3;
    const float* cj = centers + (b*28 + j)*3;
    float dx = mi*ci[0] - mj*cj[0];
    float dy = mi*ci[1] - mj*cj[1];
    float dz = mi*ci[2] - mj*cj[2];
    #pragma unroll
    for (int c8=0; c8<4; ++c8){
      int e0 = sub*32 + c8*8;
      f32x4 w0 = *(const f32x4*)&Wr[e0*3 +  0];
      f32x4 w1 = *(const f32x4*)&Wr[e0*3 +  4];
      f32x4 w2 = *(const f32x4*)&Wr[e0*3 +  8];
      f32x4 w3 = *(const f32x4*)&Wr[e0*3 + 12];
      f32x4 w4 = *(const f32x4*)&Wr[e0*3 + 16];
      f32x4 w5 = *(const f32x4*)&Wr[e0*3 + 20];
      f32x4 b0 = *(const f32x4*)&br[e0];
      f32x4 b1 = *(const f32x4*)&br[e0+4];
      b0 *= vm; b1 *= vm;   // invalid rows: dx=dy=dz=0 and b=0 -> v=0
      float v0 = dx*w0[0] + dy*w0[1] + dz*w0[2] + b0[0];
      float v1 = dx*w0[3] + dy*w1[0] + dz*w1[1] + b0[1];
      float v2 = dx*w1[2] + dy*w1[3] + dz*w2[0] + b0[2];
      float v3 = dx*w2[1] + dy*w2[2] + dz*w2[3] + b0[3];
      float v4 = dx*w3[0] + dy*w3[1] + dz*w3[2] + b1[0];
      float v5 = dx*w3[3] + dy*w4[0] + dz*w4[1] + b1[1];
      float v6 = dx*w4[2] + dy*w4[3] + dz*w5[0] + b1[2];
      float v7 = dx*w5[1] + dy*w5[2] + dz*w5[3] + b1[3];
      uint4 pw;
      pw.x = pk2(v0,v1); pw.y = pk2(v2,v3); pw.z = pk2(v4,v5); pw.w = pk2(v6,v7);
      *(uint4*)&Xa[xsw(m, e0)] = pw;
    }
  }
  __syncthreads();

  f32x4 Ya[4][2];
  #pragma unroll 1
  for (int l=0; l<3; ++l){
    // At PREFETCH for this layer's S2 -- issued BEFORE GEMM1 (independent of Xa).
    uint2 rAi[4][2], rAj[4][2];
    #pragma unroll
    for (int mt=0; mt<4; ++mt){
      rAi[mt][0] = *(const uint2*)&apI[mt][0];
      rAi[mt][1] = *(const uint2*)&apI[mt][16];
      rAj[mt][0] = *(const uint2*)&apJ[mt][0];
      rAj[mt][1] = *(const uint2*)&apJ[mt][16];
      apI[mt] += 7168*512; apJ[mt] += 7168*512;
    }
    // GEMM1: Wgr_r x rlf(Xa)^T -- then S2 writes Yb (no barrier in between)
    GEMM_TILE64(Xa, Wgrr);
    // S2: rlf_lin = Y + (Ai+bgr) + Aj -> Yb (vector adds + 8B packed writes)
    #pragma unroll
    for (int nt2=0; nt2<2; ++nt2){
      #pragma unroll
      for (int mt=0; mt<4; ++mt){
        uint2 wi = rAi[mt][nt2], wj = rAj[mt][nt2];
        f32x4 ai, aj;
        ai[0] = u2f(wi.x << 16); ai[1] = u2f(wi.x & 0xffff0000u);
        ai[2] = u2f(wi.y << 16); ai[3] = u2f(wi.y & 0xffff0000u);
        aj[0] = u2f(wj.x << 16); aj[1] = u2f(wj.x & 0xffff0000u);
        aj[2] = u2f(wj.y << 16); aj[3] = u2f(wj.y & 0xffff0000u);
        f32x4 v = Ya[mt][nt2] + ai + aj;
        *(uint2*)&Yb[woff[mt][nt2]] = make_uint2(pk2(v[0],v[1]), pk2(v[2],v[3]));
      }
    }
    __syncthreads();   // Yb complete before GEMM2 reads it
    // GEMM2: Wbc x rlf_lin(Yb)^T -- then S4 writes Xa (no barrier in between)
    GEMM_TILE64(Yb, Wbc);
    // S4: rlf = tanh(rl*c1 + (Ya*c2 + cbb)) * pv -> Xa
    #pragma unroll
    for (int nt2=0; nt2<2; ++nt2){
      #pragma unroll
      for (int mt=0; mt<4; ++mt){
        uint2 w = *(const uint2*)&Yb[woff[mt][nt2]];
        f32x4 rl;
        rl[0] = u2f(w.x << 16); rl[1] = u2f(w.x & 0xffff0000u);
        rl[2] = u2f(w.y << 16); rl[3] = u2f(w.y & 0xffff0000u);
        f32x4 bez = Ya[mt][nt2]*c2 + cbb[nt2];
        bez = rl*c1 + bez;
        float x0 = tanh_f(bez[0]) * pv[mt];
        float x1 = tanh_f(bez[1]) * pv[mt];
        float x2 = tanh_f(bez[2]) * pv[mt];
        float x3 = tanh_f(bez[3]) * pv[mt];
        *(uint2*)&Xa[woff[mt][nt2]] = make_uint2(pk2(x0,x1), pk2(x2,x3));
      }
    }
    __syncthreads();   // Xa complete before next GEMM1; fences Yb readers vs next S2
  }
  // S5: resa = Wesa x rlf(Xa)^T + besa -> v to Yb, E=exp(v) to Xa,
  // and in-register SB column partial sums (unrounded E).
  GEMM_TILE64(Xa, Wesa);
  __syncthreads();   // all GEMM reads of Xa(rlf) done before E overwrites it
  f32x4 sbp[2] = {(f32x4){0.f,0.f,0.f,0.f}, (f32x4){0.f,0.f,0.f,0.f}};
  const float m3f = (col < 8) ? 1.f : 0.f;   // mt=3 rows 48+col: valid iff col<8
  #pragma unroll
  for (int nt2=0; nt2<2; ++nt2){
    #pragma unroll
    for (int mt=0; mt<4; ++mt){
      f32x4 v = Ya[mt][nt2] + bev[nt2];
      *(uint2*)&Yb[woff[mt][nt2]] = make_uint2(pk2(v[0],v[1]), pk2(v[2],v[3]));
      f32x4 e;
      e[0] = __expf(v[0]); e[1] = __expf(v[1]);
      e[2] = __expf(v[2]); e[3] = __expf(v[3]);
      *(uint2*)&Xa[woff[mt][nt2]] = make_uint2(pk2(e[0],e[1]), pk2(e[2],e[3]));
      f32x4 wsum = e;
      if (mt == 3) wsum *= m3f;
      sbp[nt2] += wsum;
    }
  }
  // reduce across the 8 same-parity lanes of this quad (col strides 2,4,8)
  f32x4 hr[2];
  #pragma unroll
  for (int nt2=0; nt2<2; ++nt2){
    #pragma unroll
    for (int r=0; r<4; ++r){
      float s = sbp[nt2][r];
      s += __shfl_xor(s, 2, 64);
      s += __shfl_xor(s, 4, 64);
      s += __shfl_xor(s, 8, 64);
      hr[nt2][r] = 0.5f / s;
    }
  }
  __syncthreads();
  // G[row] = exp(gscore) (reads Yb, uint4 + wmean float4); hrSBp stores (col<2)
  {
    int m = tid >> 3, sub = tid & 7;   // 8 threads per row, 32 cols each
    if (m < 56){
      float s = 0.f;
      #pragma unroll
      for (int c8=0; c8<4; ++c8){
        int e0 = sub*32 + c8*8;
        uint4 u = *(const uint4*)&Yb[xsw(m, e0)];
        f32x4 wm0 = *(const f32x4*)&wmean[e0];
        f32x4 wm1 = *(const f32x4*)&wmean[e0+4];
        s += u2f(u.x << 16)*wm0[0] + u2f(u.x & 0xffff0000u)*wm0[1]
           + u2f(u.y << 16)*wm0[2] + u2f(u.y & 0xffff0000u)*wm0[3]
           + u2f(u.z << 16)*wm1[0] + u2f(u.z & 0xffff0000u)*wm1[1]
           + u2f(u.w << 16)*wm1[2] + u2f(u.w & 0xffff0000u)*wm1[3];
      }
      s += __shfl_xor(s, 1, 64);
      s += __shfl_xor(s, 2, 64);
      s += __shfl_xor(s, 4, 64);
      if (sub == 0)
        gsbp[m] = __expf(s + (bmu[0] + bmu[1] + bmu[2])*(1.f/3.f));
    }
  }
  if (col < 2){   // jc = col; every parity lane holds the full parity sum
    #pragma unroll
    for (int nt2=0; nt2<2; ++nt2){
      #pragma unroll
      for (int r=0; r<4; ++r)
        hrSBp[col*256 + nbase + nt2*16 + quad*4 + r] = hr[nt2][r];
    }
  }
  __syncthreads();
  // hrSGp: single-wave butterfly over gsbp[0..55] (was 2-thread 28-iter loop)
  if (tid < 64){
    float g = (tid < 56) ? gsbp[tid] : 0.f;
    g += __shfl_xor(g, 2, 64);
    g += __shfl_xor(g, 4, 64);
    g += __shfl_xor(g, 8, 64);
    g += __shfl_xor(g, 16, 64);
    g += __shfl_xor(g, 32, 64);
    if (tid < 2) hrSGp[tid] = 0.5f / g;   // tid==jc: sum over same-parity rows
  }
  __syncthreads();
  // masked output: scalar-contiguous atomics (R25 form; 64 lanes cover 256B)
  for (int it = tid; it < 7168; it += 512){
    int i = it >> 8, o = it & 255;
    if (i < cb){
      float s = 0.f;
      #pragma unroll
      for (int jc=0; jc<2; ++jc){
        int row = i*2 + jc;
        int off = xsw(row, o);
        float v = b2f(Yb[off]);
        float E = b2f(Xa[off]);
        float a = E*hrSBp[jc*256+o] + gsbp[row]*hrSGp[jc];
        s += a * v;
      }
      atomicAdd(&out[((size_t)b*28 + i)*256 + o], s);
    }
  }
}

extern "C" void kernel_launch(void* const* d_in, const int* in_sizes, int n_in,
                              void* d_out, int out_size, void* d_ws, size_t ws_size,
                              hipStream_t stream){
  const float* centers = (const float*)d_in[0];
  const float* emb     = (const float*)d_in[1];
  const int*   counts  = (const int*)d_in[2];
  const float* Wr      = (const float*)d_in[3];
  const float* br      = (const float*)d_in[4];
  const float* Wih     = (const float*)d_in[5];
  const float* Whh     = (const float*)d_in[6];
  const float* bih     = (const float*)d_in[7];
  const float* bhh     = (const float*)d_in[8];
  const float* Wgr     = (const float*)d_in[9];
  const float* bgr     = (const float*)d_in[10];
  const float* Wbc     = (const float*)d_in[11];
  const float* bbc     = (const float*)d_in[12];
  const float* alpha   = (const float*)d_in[13];
  const float* Wesa    = (const float*)d_in[14];
  const float* besa    = (const float*)d_in[15];
  const float* Wmu     = (const float*)d_in[16];
  const float* bmu     = (const float*)d_in[17];
  // d_in[18], d_in[19] (Wlv, blv) are dead at eval time.

  // ws layout (49,415,168 bytes total):
  unsigned short* olf   = (unsigned short*)d_ws;                      // 3*7168*256 bf16
  unsigned short* At    = (unsigned short*)((char*)d_ws + 11010048);  // 3*7168*512 bf16
  unsigned short* zx    = (unsigned short*)((char*)d_ws + 33030144);  // 7168*1024 bf16
  unsigned short* wcv   = (unsigned short*)((char*)d_ws + 47710208);  // 851,968 bf16
  float*          wmean = (float*)((char*)d_ws + 49414144);           // 256 f32
  unsigned short* cWih  = wcv;            // 262144 (N=1024)
  unsigned short* cWhh  = wcv + 262144;   // 262144 (N=1024)
  unsigned short* cWgri = wcv + 524288;   // 65536  (N=256)
  unsigned short* cWgrj = wcv + 589824;   // 65536  (N=256)
  unsigned short* cWgrr = wcv + 655360;   // 65536  (N=256)
  unsigned short* cWbc  = wcv + 720896;   // 65536  (N=256)
  unsigned short* cWesa = wcv + 786432;   // 65536  (N=256)
  float* outp = (float*)d_out;

  unsigned short* olf1 = olf + (size_t)7168*256;
  unsigned short* olf2 = olf + (size_t)2*7168*256;
  unsigned short* At1  = At  + (size_t)7168*512;
  unsigned short* At2  = At  + (size_t)2*7168*512;

  // 1) repack + prep fused
  hipLaunchKernelGGL(k_reprep, dim3(10497), dim3(256), 0, stream,
                     Wih, Whh, Wgr, Wbc, Wesa, Wmu, wcv, wmean,
                     emb, counts, olf, outp);
  // 2) LSTM pass 1 (olf0 -> olf1) fused with A-terms layer 0 (olf0 -> At0)
  hipLaunchKernelGGL(k_xgemm, dim3(224), dim3(256), 0, stream, olf, cWih, zx);
  hipLaunchKernelGGL(k_recat, dim3(44), dim3(1024), 0, stream,
                     zx, cWhh, bih, bhh, counts, olf1, olf, cWgri, cWgrj, bgr, At);
  // 3) LSTM pass 2 (olf1 -> olf2) fused with A-terms layer 1 (olf1 -> At1)
  hipLaunchKernelGGL(k_xgemm, dim3(224), dim3(256), 0, stream, olf1, cWih, zx);
  hipLaunchKernelGGL(k_recat, dim3(44), dim3(1024), 0, stream,
                     zx, cWhh, bih, bhh, counts, olf2, olf1, cWgri, cWgrj, bgr, At1);
  // 4) A-terms layer 2 (olf2 -> At2)
  hipLaunchKernelGGL(k_aterm, dim3(112), dim3(256), 0, stream, olf2, cWgri, cWgrj, bgr, At2);
  // 5) fused relation/attention/output
  hipLaunchKernelGGL(k_mega,  dim3(3584), dim3(512), 0, stream,
                     centers, counts, Wr, br, cWgrr, bgr, cWbc, bbc, alpha,
                     cWesa, besa, wmean, bmu, At, outp);
}

// Round 15
// 1018.419 us; speedup vs baseline: 1.0222x; 1.0207x over previous
//
#include <hip/hip_runtime.h>

// ObjectMsgEncoder on MI355X. f32 I/O, bf16 MFMA internally (f32 accumulate).
// R34 RESUBMIT (R14 bench was an infra failure: "MI355X container failed
// twice" -- kernel never ran; this exact source is HW-verified at 1019.5us
// in Round 11). R34 = R31 verbatim. Register weight-cache refuted twice
// (R32 48-VGPR: +21us; R33 32-VGPR: +20us -- fixed register-pressure cost
// across the 28-step loop, not spill size). R31's config stands: Whh kt 0..1
// in LDS (128KB, -25%/launch, HW-verified), kt 2..7 streamed; aterm blocks
// co-launched with rec (R30 proved splitting costs 86us); k_mega VALU-bound
// at ~50% VALUBusy after three diet rounds. Measured structural floor.

typedef __attribute__((ext_vector_type(8))) short short8;
typedef __attribute__((ext_vector_type(4))) float f32x4;

__device__ __forceinline__ float b2f(unsigned short u){
  union { unsigned int i; float f; } v; v.i = ((unsigned int)u) << 16; return v.f;
}
__device__ __forceinline__ float u2f(unsigned int u){
  union { unsigned int i; float f; } v; v.i = u; return v.f;
}
__device__ __forceinline__ unsigned short f2b(float f){
  union { float f; unsigned int i; } v; v.f = f;
  return (unsigned short)((v.i + 0x8000u) >> 16);   // round-half-up
}
// pack two f32 -> bf16x2 (lo=bf16(lo), hi=bf16(hi)); round-half-up, 3 VALU.
__device__ __forceinline__ unsigned int pk2(float lo, float hi){
  union { float f; unsigned int i; } a, b; a.f = lo; b.f = hi;
  return __builtin_amdgcn_perm(b.i + 0x8000u, a.i + 0x8000u, 0x07060302u);
}
__device__ __forceinline__ float sigm(float x){ return 1.f/(1.f+__expf(-x)); }
__device__ __forceinline__ float tanh_f(float x){ float e = __expf(2.f*x); return 1.f - 2.f/(e+1.f); }
// LDS swizzle: 8-element (16B) chunks, phys chunk = (c&24) | ((c^row)&7).
__device__ __forceinline__ int xsw(int row, int n){
  int c = n >> 3;
  int pc = (c & 24) | ((c ^ row) & 7);
  return row*256 + pc*8 + (n & 7);
}

#define MFMA16(a,b,c) __builtin_amdgcn_mfma_f32_16x16x32_bf16((a),(b),(c),0,0,0)

// ---------------- K0: repack of 7 weight blocks + wmean, FUSED with prep ----------------
__global__ __launch_bounds__(256) void k_reprep(const float* __restrict__ Wih,
                                                const float* __restrict__ Whh,
                                                const float* __restrict__ Wgr,
                                                const float* __restrict__ Wbc,
                                                const float* __restrict__ Wesa,
                                                const float* __restrict__ Wmu,
                                                unsigned short* __restrict__ wcv,
                                                float* __restrict__ wmean,
                                                const float* __restrict__ emb,
                                                const int* __restrict__ counts,
                                                unsigned short* __restrict__ olf,
                                                float* __restrict__ out){
  if (blockIdx.x >= 3329){
    // prep part: olf0 = emb * mask (f32 -> bf16) + zero out
    int bs = blockIdx.x - 3329;     // b*28+s, 0..7167
    int b = bs / 28; int s = bs - b*28;
    int e = threadIdx.x;
    olf[(size_t)bs*256 + e] = (s < counts[b]) ? f2b(emb[(size_t)bs*256 + e]) : (unsigned short)0;
    out[(size_t)bs*256 + e] = 0.f;
    return;
  }
  int i = blockIdx.x*256 + threadIdx.x;
  if (i >= 851968){                      // tail: wmean
    int o = i - 851968;
    if (o < 256) wmean[o] = (Wmu[o] + Wmu[256+o] + Wmu[512+o]) * (1.f/3.f);
    return;
  }
  const float* s; int segbase, N, stride, off, local;
  if      (i < 262144){ s=Wih;  segbase=0;      N=1024; stride=256; off=0;   local=i; }
  else if (i < 524288){ s=Whh;  segbase=262144; N=1024; stride=256; off=0;   local=i-262144; }
  else if (i < 589824){ s=Wgr;  segbase=524288; N=256;  stride=768; off=0;   local=i-524288; }
  else if (i < 655360){ s=Wgr;  segbase=589824; N=256;  stride=768; off=256; local=i-589824; }
  else if (i < 720896){ s=Wgr;  segbase=655360; N=256;  stride=768; off=512; local=i-655360; }
  else if (i < 786432){ s=Wbc;  segbase=720896; N=256;  stride=256; off=0;   local=i-720896; }
  else                { s=Wesa; segbase=786432; N=256;  stride=256; off=0;   local=i-786432; }
  int n = local >> 8, k = local & 255;
  wcv[segbase + (((k >> 3)*N + n) << 3) + (k & 7)] = f2b(s[n*stride + off + k]);
}

// ---------------- K2a: zx = olf_l @ Wih^T  [7168,256]@[256,1024] -> bf16 ----------------
// Transposed store side (verified R24/R27): lane holds zx[m0+col][nt*16+quad*4..+3].
__global__ __launch_bounds__(256) void k_xgemm(const unsigned short* __restrict__ olf,
                                               const unsigned short* __restrict__ Wih,
                                               unsigned short* __restrict__ zx){
  const int tid = threadIdx.x;
  const int wid = tid >> 6, lane = tid & 63, col = lane & 15, quad = lane >> 4;
  const int m0 = (blockIdx.x >> 1)*64 + wid*16;
  const int nt0 = (blockIdx.x & 1)*32;
  short8 af[8];
  #pragma unroll
  for (int kt=0; kt<8; ++kt)
    af[kt] = *(const short8*)&olf[(size_t)(m0 + col)*256 + kt*32 + quad*8];
  #pragma unroll 4
  for (int nt=nt0; nt<nt0+32; ++nt){
    int n = nt*16 + col;
    f32x4 acc = (f32x4){0.f,0.f,0.f,0.f};
    #pragma unroll
    for (int kt=0; kt<8; ++kt){
      short8 bf = *(const short8*)&Wih[((((kt*4 + quad) << 10) + n) << 3)];
      acc = MFMA16(bf, af[kt], acc);
    }
    *(uint2*)&zx[(size_t)(m0 + col)*1024 + nt*16 + quad*4] =
        make_uint2(pk2(acc[0],acc[1]), pk2(acc[2],acc[3]));
  }
}

// ---------------- K2b: FUSED recurrence + A-terms (i-half gets +bgr folded) ----------------
// rec branch: kt<2 slice of Whh (128KB) cached in LDS (filled once); kt>=2 from L2.
__global__ __launch_bounds__(1024) void k_recat(const unsigned short* __restrict__ zx,
                                                const unsigned short* __restrict__ Whh,
                                                const float* __restrict__ bih,
                                                const float* __restrict__ bhh,
                                                const int* __restrict__ counts,
                                                unsigned short* __restrict__ olf_out,
                                                const unsigned short* __restrict__ olf_at,
                                                const unsigned short* __restrict__ Wgri,
                                                const unsigned short* __restrict__ Wgrj,
                                                const float* __restrict__ bgr,
                                                unsigned short* __restrict__ At_out){
  __shared__ unsigned short Ab[2][16*264];   // used by rec blocks only
  __shared__ unsigned short Wlds[8192*8];    // Whh chunks c in [0,8192) == kt 0..1 (128 KB)
  const int tid = threadIdx.x;
  const int wv = tid >> 6, lane = tid & 63, col = lane & 15, quad = lane >> 4;

  if (blockIdx.x >= 16){
    // ---- aterm part: 16 waves x 16 rows, transposed store side (R27) ----
    const int m0 = (blockIdx.x - 16)*256 + wv*16;
    short8 af[8];
    #pragma unroll
    for (int kt=0; kt<8; ++kt)
      af[kt] = *(const short8*)&olf_at[(size_t)(m0 + col)*256 + kt*32 + quad*8];
    #pragma unroll 4
    for (int nt=0; nt<32; ++nt){
      const unsigned short* wb = (nt < 16) ? Wgri : Wgrj;
      int nb = (nt < 16) ? 0 : 256;
      int nn = (nt & 15)*16 + col;
      f32x4 bg4 = (nt < 16) ? *(const f32x4*)&bgr[(nt & 15)*16 + quad*4]
                            : (f32x4){0.f,0.f,0.f,0.f};
      f32x4 acc = (f32x4){0.f,0.f,0.f,0.f};
      #pragma unroll
      for (int kt=0; kt<8; ++kt){
        short8 bf = *(const short8*)&wb[((((kt*4 + quad) << 8) + nn) << 3)];
        acc = MFMA16(bf, af[kt], acc);
      }
      acc += bg4;
      *(uint2*)&At_out[(size_t)(m0 + col)*512 + nb + (nt & 15)*16 + quad*4] =
          make_uint2(pk2(acc[0],acc[1]), pk2(acc[2],acc[3]));
    }
    return;
  }
  // ---- recurrence part (R29 body + LDS weight cache) ----
  const int sc0 = blockIdx.x * 16;
  const int u = wv*16 + col;
  float bz[4];
  #pragma unroll
  for (int g=0; g<4; ++g) bz[g] = bih[g*256+u] + bhh[g*256+u];
  int cnt4[4];
  #pragma unroll
  for (int r=0; r<4; ++r) cnt4[r] = counts[sc0 + quad*4 + r];

  float cst[4];
  #pragma unroll
  for (int r=0; r<4; ++r) cst[r] = 0.f;
  for (int i=tid; i<16*264; i+=1024) Ab[0][i] = 0;   // h0 = 0
  // one-time Whh kt<2 slice -> LDS (8192 chunks x 16B = 128 KB)
  for (int c = tid; c < 8192; c += 1024)
    *(uint4*)&Wlds[c << 3] = *(const uint4*)&Whh[c << 3];
  __syncthreads();

  for (int t=0; t<28; ++t){
    const int cur = t & 1, nxt = cur ^ 1;
    float zxv[4][4];
    #pragma unroll
    for (int g=0; g<4; ++g){
      #pragma unroll
      for (int r=0; r<4; ++r)
        zxv[g][r] = b2f(zx[((size_t)(sc0 + quad*4 + r)*28 + t)*1024 + g*256 + u]);
    }
    f32x4 acc[4];
    #pragma unroll
    for (int g=0; g<4; ++g) acc[g] = (f32x4){0.f,0.f,0.f,0.f};
    #pragma unroll
    for (int kt=0; kt<8; ++kt){
      short8 a = *(const short8*)&Ab[cur][col*264 + kt*32 + quad*8];
      #pragma unroll
      for (int g=0; g<4; ++g){
        int cidx = (((kt*4 + quad) << 10) + g*256 + u);
        short8 bf = (kt < 2) ? *(const short8*)&Wlds[cidx << 3]
                             : *(const short8*)&Whh[cidx << 3];
        acc[g] = MFMA16(a, bf, acc[g]);
      }
    }
    // no barrier: writes go to Ab[nxt], readers used Ab[cur]
    #pragma unroll
    for (int r=0; r<4; ++r){
      int s = quad*4 + r;
      float zi = acc[0][r] + zxv[0][r] + bz[0];
      float zf = acc[1][r] + zxv[1][r] + bz[1];
      float zg = acc[2][r] + zxv[2][r] + bz[2];
      float zo = acc[3][r] + zxv[3][r] + bz[3];
      float cc = sigm(zf)*cst[r] + sigm(zi)*tanh_f(zg);
      cst[r] = cc;
      float hh = sigm(zo)*tanh_f(cc);
      unsigned short hb = f2b(hh);
      Ab[nxt][s*264 + u] = hb;                              // raw h feeds recurrence
      olf_out[((size_t)(sc0+s)*28 + t)*256 + u] = (t < cnt4[r]) ? hb : (unsigned short)0;
    }
    __syncthreads();   // Ab[nxt] complete before step t+1 reads it
  }
}

// ---------------- K3: A-terms for ONE layer, transposed store side ----------------
__global__ __launch_bounds__(256) void k_aterm(const unsigned short* __restrict__ olf,
                                               const unsigned short* __restrict__ Wgri,
                                               const unsigned short* __restrict__ Wgrj,
                                               const float* __restrict__ bgr,
                                               unsigned short* __restrict__ Aout){
  const int tid = threadIdx.x;
  const int wid = tid >> 6, lane = tid & 63, col = lane & 15, quad = lane >> 4;
  const int m0 = blockIdx.x*64 + wid*16;
  short8 af[8];
  #pragma unroll
  for (int kt=0; kt<8; ++kt)
    af[kt] = *(const short8*)&olf[(size_t)(m0 + col)*256 + kt*32 + quad*8];
  #pragma unroll 4
  for (int nt=0; nt<32; ++nt){
    const unsigned short* wb = (nt < 16) ? Wgri : Wgrj;
    int nb = (nt < 16) ? 0 : 256;
    int nn = (nt & 15)*16 + col;
    f32x4 bg4 = (nt < 16) ? *(const f32x4*)&bgr[(nt & 15)*16 + quad*4]
                          : (f32x4){0.f,0.f,0.f,0.f};
    f32x4 acc = (f32x4){0.f,0.f,0.f,0.f};
    #pragma unroll
    for (int kt=0; kt<8; ++kt){
      short8 bf = *(const short8*)&wb[((((kt*4 + quad) << 8) + nn) << 3)];
      acc = MFMA16(bf, af[kt], acc);
    }
    acc += bg4;
    *(uint2*)&Aout[(size_t)(m0 + col)*512 + nb + (nt & 15)*16 + quad*4] =
        make_uint2(pk2(acc[0],acc[1]), pk2(acc[2],acc[3]));
  }
}

// ---------------- K4: fused per-(scene, j-pair), transposed-output GEMMs ----------------
#define GEMM_TILE64(SRC, WPTR)                                                      \
  {                                                                                 \
    _Pragma("unroll")                                                               \
    for (int rf=0; rf<4; ++rf){ Ya[rf][0]=(f32x4){0.f,0.f,0.f,0.f};                 \
                                Ya[rf][1]=(f32x4){0.f,0.f,0.f,0.f}; }               \
    _Pragma("unroll 1")                                                             \
    for (int kc=0; kc<4; ++kc){                                                     \
      short8 av[2][4], bv[2][2];                                                    \
      _Pragma("unroll")                                                             \
      for (int u=0; u<2; ++u){                                                      \
        int kt = kc*2 + u;                                                          \
        _Pragma("unroll")                                                           \
        for (int rf=0; rf<4; ++rf)                                                  \
          av[u][rf] = *(const short8*)&(SRC)[(Abase[rf] + kc*64) ^ (u*32)];         \
        bv[u][0] = *(const short8*)&(WPTR)[Bbase + kt*8192];                        \
        bv[u][1] = *(const short8*)&(WPTR)[Bbase + kt*8192 + 128];                  \
      }                                                                             \
      __builtin_amdgcn_s_setprio(1);                                                \
      _Pragma("unroll")                                                             \
      for (int u=0; u<2; ++u){                                                      \
        _Pragma("unroll")                                                           \
        for (int rf=0; rf<4; ++rf){                                                 \
          Ya[rf][0] = MFMA16(bv[u][0], av[u][rf], Ya[rf][0]);                       \
          Ya[rf][1] = MFMA16(bv[u][1], av[u][rf], Ya[rf][1]);                       \
        }                                                                           \
      }                                                                             \
      __builtin_amdgcn_s_setprio(0);                                                \
    }                                                                               \
  }

__global__ __launch_bounds__(512, 4) void k_mega(
    const float* __restrict__ centers, const int* __restrict__ counts,
    const float* __restrict__ Wr, const float* __restrict__ br,
    const unsigned short* __restrict__ Wgrr, const float* __restrict__ bgr,
    const unsigned short* __restrict__ Wbc, const float* __restrict__ bbc,
    const float* __restrict__ alpha,
    const unsigned short* __restrict__ Wesa, const float* __restrict__ besa,
    const float* __restrict__ wmean, const float* __restrict__ bmu,
    const unsigned short* __restrict__ Aterm, float* __restrict__ out){
  __shared__ unsigned short Xa[64*256];    // rlf -> E=exp(resa); rows 56..63 pad/stats
  __shared__ unsigned short Yb[64*256];    // rlf_lin / resa
  float* hrSBp = (float*)&Xa[56*256];      // 512 f32 [jc*256+o]: 0.5/sum_i E
  float* gsbp  = (float*)&Xa[60*256];      // 64 f32 per row p: G = exp(gscore)
  float* hrSGp = (float*)&Xa[60*256+128];  // 2 f32 per jc: 0.5/sum_i G
  const int tid = threadIdx.x;
  const int wv = tid >> 6;          // 0..7 -> col slice
  const int lane = tid & 63, col = lane & 15, quad = lane >> 4;
  // XCD-aware swizzle: all 14 jt-blocks of scene b land on the same XCD
  const int xcd = blockIdx.x & 7, idx = blockIdx.x >> 3;   // idx 0..447
  const int b = xcd*32 + idx/14, jt = idx - (idx/14)*14;   // j = jt*2 + jc
  const int cb = counts[b];
  const int nbase = wv*32;

  float av_ = alpha[0];
  float tv = sigm(av_);
  float c1 = (1.f-tv)*(1.f-tv) + tv*tv;
  float c2 = 2.f*tv*(1.f-tv);

  // per-thread row mapping for transposed fragments: m = mt*16 + col
  float pv[4];
  const unsigned short* apI[4];
  const unsigned short* apJ[4];
  #pragma unroll
  for (int mt=0; mt<4; ++mt){
    int m = mt*16 + col;
    int i = m >> 1;
    int pi = (i < 27) ? i : 27;
    int pj = jt*2 + (m & 1);
    pv[mt] = (m < 56 && i < cb && pj < cb) ? 1.f : 0.f;
    apI[mt] = Aterm + (size_t)(b*28 + pi)*512 + nbase + quad*4;
    apJ[mt] = Aterm + (size_t)(b*28 + pj)*512 + 256 + nbase + quad*4;
  }
  // hoisted swizzled addresses (reused across all 7 GEMMs / 3 layers)
  int Abase[4];
  #pragma unroll
  for (int rf=0; rf<4; ++rf){
    int row = rf*16 + col;
    Abase[rf] = row*256 + ((quad ^ (row & 3)) | (row & 4))*8;
  }
  const int Bbase = (quad*256 + nbase + col)*8;
  int woff[4][2];
  f32x4 cbb[2], bev[2];
  #pragma unroll
  for (int nt2=0; nt2<2; ++nt2){
    int n0 = nbase + nt2*16 + quad*4;
    cbb[nt2] = (*(const f32x4*)&bbc[n0]) * c2;   // c2*bbc hoisted for S4
    bev[nt2] = *(const f32x4*)&besa[n0];
    #pragma unroll
    for (int mt=0; mt<4; ++mt)
      woff[mt][nt2] = xsw(mt*16 + col, n0);
  }

  // S0: rlf0[row] -> Xa ; pad rows = 0. Vectorized: float4 Wr/br, uint4 writes.
  {
    int m = tid >> 3, sub = tid & 7;   // m 0..63, 32 cols each
    int i = m >> 1, j = jt*2 + (m & 1);
    bool valid = (m < 56);
    float mi = (valid && i < cb) ? 1.f : 0.f;
    float mj = (valid && j < cb) ? 1.f : 0.f;
    float vm = valid ? 1.f : 0.f;
    const float* ci = centers + (b*28 + (valid ? i : 0))*3;
    const float* cj = centers + (b*28 + j)*3;
    float dx = mi*ci[0] - mj*cj[0];
    float dy = mi*ci[1] - mj*cj[1];
    float dz = mi*ci[2] - mj*cj[2];
    #pragma unroll
    for (int c8=0; c8<4; ++c8){
      int e0 = sub*32 + c8*8;
      f32x4 w0 = *(const f32x4*)&Wr[e0*3 +  0];
      f32x4 w1 = *(const f32x4*)&Wr[e0*3 +  4];
      f32x4 w2 = *(const f32x4*)&Wr[e0*3 +  8];
      f32x4 w3 = *(const f32x4*)&Wr[e0*3 + 12];
      f32x4 w4 = *(const f32x4*)&Wr[e0*3 + 16];
      f32x4 w5 = *(const f32x4*)&Wr[e0*3 + 20];
      f32x4 b0 = *(const f32x4*)&br[e0];
      f32x4 b1 = *(const f32x4*)&br[e0+4];
      b0 *= vm; b1 *= vm;   // invalid rows: dx=dy=dz=0 and b=0 -> v=0
      float v0 = dx*w0[0] + dy*w0[1] + dz*w0[2] + b0[0];
      float v1 = dx*w0[3] + dy*w1[0] + dz*w1[1] + b0[1];
      float v2 = dx*w1[2] + dy*w1[3] + dz*w2[0] + b0[2];
      float v3 = dx*w2[1] + dy*w2[2] + dz*w2[3] + b0[3];
      float v4 = dx*w3[0] + dy*w3[1] + dz*w3[2] + b1[0];
      float v5 = dx*w3[3] + dy*w4[0] + dz*w4[1] + b1[1];
      float v6 = dx*w4[2] + dy*w4[3] + dz*w5[0] + b1[2];
      float v7 = dx*w5[1] + dy*w5[2] + dz*w5[3] + b1[3];
      uint4 pw;
      pw.x = pk2(v0,v1); pw.y = pk2(v2,v3); pw.z = pk2(v4,v5); pw.w = pk2(v6,v7);
      *(uint4*)&Xa[xsw(m, e0)] = pw;
    }
  }
  __syncthreads();

  f32x4 Ya[4][2];
  #pragma unroll 1
  for (int l=0; l<3; ++l){
    // At PREFETCH for this layer's S2 -- issued BEFORE GEMM1 (independent of Xa).
    uint2 rAi[4][2], rAj[4][2];
    #pragma unroll
    for (int mt=0; mt<4; ++mt){
      rAi[mt][0] = *(const uint2*)&apI[mt][0];
      rAi[mt][1] = *(const uint2*)&apI[mt][16];
      rAj[mt][0] = *(const uint2*)&apJ[mt][0];
      rAj[mt][1] = *(const uint2*)&apJ[mt][16];
      apI[mt] += 7168*512; apJ[mt] += 7168*512;
    }
    // GEMM1: Wgr_r x rlf(Xa)^T -- then S2 writes Yb (no barrier in between)
    GEMM_TILE64(Xa, Wgrr);
    // S2: rlf_lin = Y + (Ai+bgr) + Aj -> Yb (vector adds + 8B packed writes)
    #pragma unroll
    for (int nt2=0; nt2<2; ++nt2){
      #pragma unroll
      for (int mt=0; mt<4; ++mt){
        uint2 wi = rAi[mt][nt2], wj = rAj[mt][nt2];
        f32x4 ai, aj;
        ai[0] = u2f(wi.x << 16); ai[1] = u2f(wi.x & 0xffff0000u);
        ai[2] = u2f(wi.y << 16); ai[3] = u2f(wi.y & 0xffff0000u);
        aj[0] = u2f(wj.x << 16); aj[1] = u2f(wj.x & 0xffff0000u);
        aj[2] = u2f(wj.y << 16); aj[3] = u2f(wj.y & 0xffff0000u);
        f32x4 v = Ya[mt][nt2] + ai + aj;
        *(uint2*)&Yb[woff[mt][nt2]] = make_uint2(pk2(v[0],v[1]), pk2(v[2],v[3]));
      }
    }
    __syncthreads();   // Yb complete before GEMM2 reads it
    // GEMM2: Wbc x rlf_lin(Yb)^T -- then S4 writes Xa (no barrier in between)
    GEMM_TILE64(Yb, Wbc);
    // S4: rlf = tanh(rl*c1 + (Ya*c2 + cbb)) * pv -> Xa
    #pragma unroll
    for (int nt2=0; nt2<2; ++nt2){
      #pragma unroll
      for (int mt=0; mt<4; ++mt){
        uint2 w = *(const uint2*)&Yb[woff[mt][nt2]];
        f32x4 rl;
        rl[0] = u2f(w.x << 16); rl[1] = u2f(w.x & 0xffff0000u);
        rl[2] = u2f(w.y << 16); rl[3] = u2f(w.y & 0xffff0000u);
        f32x4 bez = Ya[mt][nt2]*c2 + cbb[nt2];
        bez = rl*c1 + bez;
        float x0 = tanh_f(bez[0]) * pv[mt];
        float x1 = tanh_f(bez[1]) * pv[mt];
        float x2 = tanh_f(bez[2]) * pv[mt];
        float x3 = tanh_f(bez[3]) * pv[mt];
        *(uint2*)&Xa[woff[mt][nt2]] = make_uint2(pk2(x0,x1), pk2(x2,x3));
      }
    }
    __syncthreads();   // Xa complete before next GEMM1; fences Yb readers vs next S2
  }
  // S5: resa = Wesa x rlf(Xa)^T + besa -> v to Yb, E=exp(v) to Xa,
  // and in-register SB column partial sums (unrounded E).
  GEMM_TILE64(Xa, Wesa);
  __syncthreads();   // all GEMM reads of Xa(rlf) done before E overwrites it
  f32x4 sbp[2] = {(f32x4){0.f,0.f,0.f,0.f}, (f32x4){0.f,0.f,0.f,0.f}};
  const float m3f = (col < 8) ? 1.f : 0.f;   // mt=3 rows 48+col: valid iff col<8
  #pragma unroll
  for (int nt2=0; nt2<2; ++nt2){
    #pragma unroll
    for (int mt=0; mt<4; ++mt){
      f32x4 v = Ya[mt][nt2] + bev[nt2];
      *(uint2*)&Yb[woff[mt][nt2]] = make_uint2(pk2(v[0],v[1]), pk2(v[2],v[3]));
      f32x4 e;
      e[0] = __expf(v[0]); e[1] = __expf(v[1]);
      e[2] = __expf(v[2]); e[3] = __expf(v[3]);
      *(uint2*)&Xa[woff[mt][nt2]] = make_uint2(pk2(e[0],e[1]), pk2(e[2],e[3]));
      f32x4 wsum = e;
      if (mt == 3) wsum *= m3f;
      sbp[nt2] += wsum;
    }
  }
  // reduce across the 8 same-parity lanes of this quad (col strides 2,4,8)
  f32x4 hr[2];
  #pragma unroll
  for (int nt2=0; nt2<2; ++nt2){
    #pragma unroll
    for (int r=0; r<4; ++r){
      float s = sbp[nt2][r];
      s += __shfl_xor(s, 2, 64);
      s += __shfl_xor(s, 4, 64);
      s += __shfl_xor(s, 8, 64);
      hr[nt2][r] = 0.5f / s;
    }
  }
  __syncthreads();
  // G[row] = exp(gscore) (reads Yb, uint4 + wmean float4); hrSBp stores (col<2)
  {
    int m = tid >> 3, sub = tid & 7;   // 8 threads per row, 32 cols each
    if (m < 56){
      float s = 0.f;
      #pragma unroll
      for (int c8=0; c8<4; ++c8){
        int e0 = sub*32 + c8*8;
        uint4 u = *(const uint4*)&Yb[xsw(m, e0)];
        f32x4 wm0 = *(const f32x4*)&wmean[e0];
        f32x4 wm1 = *(const f32x4*)&wmean[e0+4];
        s += u2f(u.x << 16)*wm0[0] + u2f(u.x & 0xffff0000u)*wm0[1]
           + u2f(u.y << 16)*wm0[2] + u2f(u.y & 0xffff0000u)*wm0[3]
           + u2f(u.z << 16)*wm1[0] + u2f(u.z & 0xffff0000u)*wm1[1]
           + u2f(u.w << 16)*wm1[2] + u2f(u.w & 0xffff0000u)*wm1[3];
      }
      s += __shfl_xor(s, 1, 64);
      s += __shfl_xor(s, 2, 64);
      s += __shfl_xor(s, 4, 64);
      if (sub == 0)
        gsbp[m] = __expf(s + (bmu[0] + bmu[1] + bmu[2])*(1.f/3.f));
    }
  }
  if (col < 2){   // jc = col; every parity lane holds the full parity sum
    #pragma unroll
    for (int nt2=0; nt2<2; ++nt2){
      #pragma unroll
      for (int r=0; r<4; ++r)
        hrSBp[col*256 + nbase + nt2*16 + quad*4 + r] = hr[nt2][r];
    }
  }
  __syncthreads();
  // hrSGp: single-wave butterfly over gsbp[0..55] (was 2-thread 28-iter loop)
  if (tid < 64){
    float g = (tid < 56) ? gsbp[tid] : 0.f;
    g += __shfl_xor(g, 2, 64);
    g += __shfl_xor(g, 4, 64);
    g += __shfl_xor(g, 8, 64);
    g += __shfl_xor(g, 16, 64);
    g += __shfl_xor(g, 32, 64);
    if (tid < 2) hrSGp[tid] = 0.5f / g;   // tid==jc: sum over same-parity rows
  }
  __syncthreads();
  // masked output: scalar-contiguous atomics (R25 form; 64 lanes cover 256B)
  for (int it = tid; it < 7168; it += 512){
    int i = it >> 8, o = it & 255;
    if (i < cb){
      float s = 0.f;
      #pragma unroll
      for (int jc=0; jc<2; ++jc){
        int row = i*2 + jc;
        int off = xsw(row, o);
        float v = b2f(Yb[off]);
        float E = b2f(Xa[off]);
        float a = E*hrSBp[jc*256+o] + gsbp[row]*hrSGp[jc];
        s += a * v;
      }
      atomicAdd(&out[((size_t)b*28 + i)*256 + o], s);
    }
  }
}

extern "C" void kernel_launch(void* const* d_in, const int* in_sizes, int n_in,
                              void* d_out, int out_size, void* d_ws, size_t ws_size,
                              hipStream_t stream){
  const float* centers = (const float*)d_in[0];
  const float* emb     = (const float*)d_in[1];
  const int*   counts  = (const int*)d_in[2];
  const float* Wr      = (const float*)d_in[3];
  const float* br      = (const float*)d_in[4];
  const float* Wih     = (const float*)d_in[5];
  const float* Whh     = (const float*)d_in[6];
  const float* bih     = (const float*)d_in[7];
  const float* bhh     = (const float*)d_in[8];
  const float* Wgr     = (const float*)d_in[9];
  const float* bgr     = (const float*)d_in[10];
  const float* Wbc     = (const float*)d_in[11];
  const float* bbc     = (const float*)d_in[12];
  const float* alpha   = (const float*)d_in[13];
  const float* Wesa    = (const float*)d_in[14];
  const float* besa    = (const float*)d_in[15];
  const float* Wmu     = (const float*)d_in[16];
  const float* bmu     = (const float*)d_in[17];
  // d_in[18], d_in[19] (Wlv, blv) are dead at eval time.

  // ws layout (49,415,168 bytes total):
  unsigned short* olf   = (unsigned short*)d_ws;                      // 3*7168*256 bf16
  unsigned short* At    = (unsigned short*)((char*)d_ws + 11010048);  // 3*7168*512 bf16
  unsigned short* zx    = (unsigned short*)((char*)d_ws + 33030144);  // 7168*1024 bf16
  unsigned short* wcv   = (unsigned short*)((char*)d_ws + 47710208);  // 851,968 bf16
  float*          wmean = (float*)((char*)d_ws + 49414144);           // 256 f32
  unsigned short* cWih  = wcv;            // 262144 (N=1024)
  unsigned short* cWhh  = wcv + 262144;   // 262144 (N=1024)
  unsigned short* cWgri = wcv + 524288;   // 65536  (N=256)
  unsigned short* cWgrj = wcv + 589824;   // 65536  (N=256)
  unsigned short* cWgrr = wcv + 655360;   // 65536  (N=256)
  unsigned short* cWbc  = wcv + 720896;   // 65536  (N=256)
  unsigned short* cWesa = wcv + 786432;   // 65536  (N=256)
  float* outp = (float*)d_out;

  unsigned short* olf1 = olf + (size_t)7168*256;
  unsigned short* olf2 = olf + (size_t)2*7168*256;
  unsigned short* At1  = At  + (size_t)7168*512;
  unsigned short* At2  = At  + (size_t)2*7168*512;

  // 1) repack + prep fused
  hipLaunchKernelGGL(k_reprep, dim3(10497), dim3(256), 0, stream,
                     Wih, Whh, Wgr, Wbc, Wesa, Wmu, wcv, wmean,
                     emb, counts, olf, outp);
  // 2) LSTM pass 1 (olf0 -> olf1) fused with A-terms layer 0 (olf0 -> At0)
  hipLaunchKernelGGL(k_xgemm, dim3(224), dim3(256), 0, stream, olf, cWih, zx);
  hipLaunchKernelGGL(k_recat, dim3(44), dim3(1024), 0, stream,
                     zx, cWhh, bih, bhh, counts, olf1, olf, cWgri, cWgrj, bgr, At);
  // 3) LSTM pass 2 (olf1 -> olf2) fused with A-terms layer 1 (olf1 -> At1)
  hipLaunchKernelGGL(k_xgemm, dim3(224), dim3(256), 0, stream, olf1, cWih, zx);
  hipLaunchKernelGGL(k_recat, dim3(44), dim3(1024), 0, stream,
                     zx, cWhh, bih, bhh, counts, olf2, olf1, cWgri, cWgrj, bgr, At1);
  // 4) A-terms layer 2 (olf2 -> At2)
  hipLaunchKernelGGL(k_aterm, dim3(112), dim3(256), 0, stream, olf2, cWgri, cWgrj, bgr, At2);
  // 5) fused relation/attention/output
  hipLaunchKernelGGL(k_mega,  dim3(3584), dim3(512), 0, stream,
                     centers, counts, Wr, br, cWgrr, bgr, cWbc, bbc, alpha,
                     cWesa, besa, wmean, bmu, At, outp);
}